// Round 10
// baseline (303.894 us; speedup 1.0000x reference)
//
#include <hip/hip_runtime.h>
#include <hip/hip_fp16.h>

#define NEG_SLOPE 0.2f
#define EPSF 1e-16f

// ---------- GEMM + fused alpha epilogue ----------
template<int BN, int HEADS, bool OUTH, typename XT>
__global__ __launch_bounds__(256) void gemm_fused(const XT* __restrict__ X,
                                                  const float* __restrict__ W,
                                                  const float* __restrict__ asrc,
                                                  const float* __restrict__ adst,
                                                  float* __restrict__ OutF,
                                                  __half* __restrict__ OutH,
                                                  float* __restrict__ AS,
                                                  float* __restrict__ AD, int N) {
    constexpr int BM = 64, BK = 32, K = 128;
    constexpr int TN = BN / 16;  // 8 (BN=128) or 4 (BN=64)
    __shared__ float Xs[BM][BK + 4];
    __shared__ float Ws[BK][BN];
    const int tid = threadIdx.x;
    const int tx = tid & 15, ty = tid >> 4;
    const int row0 = blockIdx.x * BM;

    float acc[4][TN];
#pragma unroll
    for (int i = 0; i < 4; ++i)
#pragma unroll
        for (int j = 0; j < TN; ++j) acc[i][j] = 0.f;

    for (int kb = 0; kb < K; kb += BK) {
        __syncthreads();
        for (int idx = tid; idx < BK * (BN / 4); idx += 256) {
            int r = idx / (BN / 4), c4 = idx % (BN / 4);
            ((float4*)&Ws[r][0])[c4] = ((const float4*)&W[(size_t)(kb + r) * BN])[c4];
        }
        for (int t = tid; t < BM * (BK / 4); t += 256) {
            int r = t >> 3, c4 = t & 7;
            int gr = row0 + r;
            float f[4] = {0.f, 0.f, 0.f, 0.f};
            if (gr < N) {
                if constexpr (sizeof(XT) == 2) {
                    uint2 raw = *((const uint2*)&X[(size_t)gr * K + kb + c4 * 4]);
                    const __half2* hp = (const __half2*)&raw;
                    float2 f0 = __half22float2(hp[0]);
                    float2 f1 = __half22float2(hp[1]);
                    f[0] = f0.x; f[1] = f0.y; f[2] = f1.x; f[3] = f1.y;
                } else {
                    float4 v = *((const float4*)&X[(size_t)gr * K + kb + c4 * 4]);
                    f[0] = v.x; f[1] = v.y; f[2] = v.z; f[3] = v.w;
                }
            }
            Xs[r][c4 * 4 + 0] = f[0]; Xs[r][c4 * 4 + 1] = f[1];
            Xs[r][c4 * 4 + 2] = f[2]; Xs[r][c4 * 4 + 3] = f[3];
        }
        __syncthreads();
#pragma unroll
        for (int k = 0; k < BK; ++k) {
            float xr[4];
#pragma unroll
            for (int i = 0; i < 4; ++i) xr[i] = Xs[ty * 4 + i][k];
            float wv[TN];
#pragma unroll
            for (int j4 = 0; j4 < TN / 4; ++j4) {
                float4 w4 = ((float4*)&Ws[k][0])[tx * (TN / 4) + j4];
                wv[j4 * 4 + 0] = w4.x; wv[j4 * 4 + 1] = w4.y;
                wv[j4 * 4 + 2] = w4.z; wv[j4 * 4 + 3] = w4.w;
            }
#pragma unroll
            for (int i = 0; i < 4; ++i)
#pragma unroll
                for (int j = 0; j < TN; ++j) acc[i][j] = fmaf(xr[i], wv[j], acc[i][j]);
        }
    }

    float av[TN], dv[TN];
#pragma unroll
    for (int j = 0; j < TN; ++j) { av[j] = asrc[tx * TN + j]; dv[j] = adst[tx * TN + j]; }

#pragma unroll
    for (int i = 0; i < 4; ++i) {
        int gr = row0 + ty * 4 + i;
        if (gr >= N) continue;
        if (OUTH) {
            __half2 hp[TN / 2];
#pragma unroll
            for (int j2 = 0; j2 < TN / 2; ++j2)
                hp[j2] = __floats2half2_rn(acc[i][j2 * 2], acc[i][j2 * 2 + 1]);
            if (TN == 8)
                *((uint4*)&OutH[(size_t)gr * BN + tx * TN]) = *(uint4*)hp;
            else
                *((uint2*)&OutH[(size_t)gr * BN + tx * TN]) = *(uint2*)hp;
        } else {
#pragma unroll
            for (int j4 = 0; j4 < TN / 4; ++j4) {
                float4 o4 = make_float4(acc[i][j4 * 4 + 0], acc[i][j4 * 4 + 1],
                                        acc[i][j4 * 4 + 2], acc[i][j4 * 4 + 3]);
                *((float4*)&OutF[(size_t)gr * BN + tx * TN + j4 * 4]) = o4;
            }
        }
        float ps = 0.f, pd = 0.f;
#pragma unroll
        for (int j = 0; j < TN; ++j) { ps = fmaf(acc[i][j], av[j], ps); pd = fmaf(acc[i][j], dv[j], pd); }
        if (HEADS == 2) {
            for (int o = 1; o < 8; o <<= 1) { ps += __shfl_xor(ps, o, 64); pd += __shfl_xor(pd, o, 64); }
            if ((tx & 7) == 0) { AS[gr * 2 + (tx >> 3)] = ps; AD[gr * 2 + (tx >> 3)] = pd; }
        } else {
            for (int o = 1; o < 16; o <<= 1) { ps += __shfl_xor(ps, o, 64); pd += __shfl_xor(pd, o, 64); }
            if (tx == 0) { AS[gr] = ps; AD[gr] = pd; }
        }
    }
}

// ---------- CSR build ----------
__global__ void zero_kernel(int* __restrict__ p, int n4) {
    int i = blockIdx.x * blockDim.x + threadIdx.x;
    if (i < n4) ((int4*)p)[i] = make_int4(0, 0, 0, 0);
}

__global__ void hist_kernel(const int* __restrict__ ei, int E_raw, int N,
                            int* __restrict__ cnt) {
    const int E = E_raw + N;
    for (int e = blockIdx.x * blockDim.x + threadIdx.x; e < E; e += gridDim.x * blockDim.x) {
        int d = (e < E_raw) ? ei[E_raw + e] : e - E_raw;
        atomicAdd(&cnt[d], 1);
    }
}

__global__ __launch_bounds__(256) void scan_block(const int* __restrict__ cnt,
                                                  int* __restrict__ offs,
                                                  int* __restrict__ bsum, int N) {
    __shared__ int wsum[4];
    const int i = blockIdx.x * 256 + threadIdx.x;
    const int lane = threadIdx.x & 63, w = threadIdx.x >> 6;
    int v = (i < N) ? cnt[i] : 0;
    int incl = v;
    for (int o = 1; o < 64; o <<= 1) {
        int t = __shfl_up(incl, o, 64);
        if (lane >= o) incl += t;
    }
    if (lane == 63) wsum[w] = incl;
    __syncthreads();
    int prefix = 0;
    for (int k = 0; k < w; ++k) prefix += wsum[k];
    if (i < N) offs[i] = prefix + incl - v;
    if (threadIdx.x == 255) bsum[blockIdx.x] = prefix + incl;
}

__global__ __launch_bounds__(256) void scan_bsum(int* __restrict__ bsum, int nb) {
    __shared__ int wsum[4];
    const int lane = threadIdx.x & 63, w = threadIdx.x >> 6;
    int v = (threadIdx.x < nb) ? bsum[threadIdx.x] : 0;
    int incl = v;
    for (int o = 1; o < 64; o <<= 1) {
        int t = __shfl_up(incl, o, 64);
        if (lane >= o) incl += t;
    }
    if (lane == 63) wsum[w] = incl;
    __syncthreads();
    int prefix = 0;
    for (int k = 0; k < w; ++k) prefix += wsum[k];
    if (threadIdx.x < nb) bsum[threadIdx.x] = prefix + incl - v;
}

__global__ void scan_add(int* __restrict__ offs, const int* __restrict__ bsum,
                         int N, int E) {
    const int i = blockIdx.x * 256 + threadIdx.x;
    if (i < N) offs[i] += bsum[blockIdx.x];
    if (i == 0) offs[N] = E;
}

// XCD-partitioned scatter (R5). pos = offs[d] + (--cnt[d]); cnt ends at 0.
__global__ void scatter_edges_part(const int* __restrict__ ei, int E_raw, int N,
                                   int* __restrict__ cnt,
                                   const int* __restrict__ offs,
                                   int* __restrict__ csr_src) {
    const int NPART = 8;
    const int part = blockIdx.x & (NPART - 1);
    const int gblocks = gridDim.x >> 3;
    const int grank = blockIdx.x >> 3;
    const int tid = grank * blockDim.x + threadIdx.x;
    const int nthr = gblocks * blockDim.x;
    const int E = E_raw + N;
    const int dlo = (int)(((long long)N * part) / NPART);
    const int dhi = (int)(((long long)N * (part + 1)) / NPART);
    for (int e = tid; e < E; e += nthr) {
        int d = (e < E_raw) ? ei[E_raw + e] : e - E_raw;
        if (d >= dlo && d < dhi) {
            int s = (e < E_raw) ? ei[e] : d;
            int old = atomicSub(&cnt[d], 1);
            csr_src[offs[d] + old - 1] = s;
        }
    }
}

// ---------- fused GAT, heads=2, fp16 H, fp16 out. HALF-WAVE per node ----------
// 32 lanes own one node (avg deg 17 -> lanes actually used). Aggregate:
// 2 edge slots x 16 lanes x 8ch (uint4), 8-deep batch = 16 gathers in
// flight per half-wave, 32 per wave, 2 nodes per wave per pass.
__global__ __launch_bounds__(256) void gat_csr2(const int* __restrict__ offs,
                                                const int* __restrict__ csr_src,
                                                const float* __restrict__ AS,
                                                const float* __restrict__ AD,
                                                const __half* __restrict__ H,
                                                const float* __restrict__ bias,
                                                __half* __restrict__ Out,
                                                int N, int do_relu) {
    __shared__ int   sS[4][64];
    __shared__ float sP0[4][64];
    __shared__ float sP1[4][64];
    const int lane = threadIdx.x & 63;
    const int w = threadIdx.x >> 6;
    const int wid = (int)((blockIdx.x * blockDim.x + threadIdx.x) >> 6);
    const int nw = (int)((gridDim.x * blockDim.x) >> 6);
    const int half = lane >> 5;   // which node of the pair
    const int hl = lane & 31;
    const int c = hl & 15;        // channels 8c..8c+7
    const int slot = hl >> 4;     // 2 edge slots per half
    const int myh = c >> 3;       // head owning my channels
    const int hbase = half * 32;
    int* const sSw = &sS[w][0];
    const float* const myp = myh ? &sP1[w][0] : &sP0[w][0];
    const float4 bA = *(const float4*)&bias[8 * c];
    const float4 bB = *(const float4*)&bias[8 * c + 4];
    const int npairs = (N + 1) >> 1;

    for (int np = wid; np < npairs; np += nw) {
        const int n = 2 * np + half;
        const bool active = (n < N);
        int s0 = 0, s1 = 0;
        float2 adv = make_float2(0.f, 0.f);
        if (active) {
            s0 = offs[n]; s1 = offs[n + 1];
            adv = *(const float2*)&AD[(size_t)n * 2];
        }
        const int deg = s1 - s0;
        float dn0 = 0.f, dn1 = 0.f, p0 = 0.f, p1 = 0.f;
        int sreg = 0;
        for (int i = s0 + hl; i < s1; i += 32) {
            int s = csr_src[i];
            float2 a2 = *(const float2*)&AS[(size_t)s * 2];
            float e0 = a2.x + adv.x, e1 = a2.y + adv.y;
            e0 = e0 > 0.f ? e0 : NEG_SLOPE * e0;
            e1 = e1 > 0.f ? e1 : NEG_SLOPE * e1;
            float pe0 = __expf(e0), pe1 = __expf(e1);
            dn0 += pe0; dn1 += pe1;
            if (i == s0 + hl) { sreg = s; p0 = pe0; p1 = pe1; }
        }
        // reduce within the 32-lane half (xor <= 16 never crosses halves)
        for (int o = 1; o < 32; o <<= 1) {
            dn0 += __shfl_xor(dn0, o, 64);
            dn1 += __shfl_xor(dn1, o, 64);
        }
        const float myinv = 1.f / ((myh ? dn1 : dn0) + EPSF);

        float a[8];
#pragma unroll
        for (int j = 0; j < 8; ++j) a[j] = 0.f;
        if (deg <= 32) {   // covers ~99.97% of Poisson(17) nodes
            sSw[lane] = sreg;       // phantom slots hold s=0, p=0
            sP0[w][lane] = p0;
            sP1[w][lane] = p1;
            const int npc = (deg + 1) >> 1;   // edge pairs (2 slots)
            int t = 0;
            for (; t + 8 <= npc; t += 8) {
                int ss[8]; float pw[8]; uint4 hv[8];
#pragma unroll
                for (int k = 0; k < 8; ++k) {
                    int idx = hbase + 2 * (t + k) + slot;
                    ss[k] = sSw[idx];
                    pw[k] = myp[idx];
                }
#pragma unroll
                for (int k = 0; k < 8; ++k)
                    hv[k] = *(const uint4*)&H[(size_t)ss[k] * 128 + 8 * c];
#pragma unroll
                for (int k = 0; k < 8; ++k) {
                    const __half2* h2 = (const __half2*)&hv[k];
#pragma unroll
                    for (int j = 0; j < 4; ++j) {
                        float2 f = __half22float2(h2[j]);
                        a[2 * j]     = fmaf(f.x, pw[k], a[2 * j]);
                        a[2 * j + 1] = fmaf(f.y, pw[k], a[2 * j + 1]);
                    }
                }
            }
            for (; t < npc; ++t) {
                int idx = hbase + 2 * t + slot;
                int s = sSw[idx];
                float pw = myp[idx];
                uint4 hv = *(const uint4*)&H[(size_t)s * 128 + 8 * c];
                const __half2* h2 = (const __half2*)&hv;
#pragma unroll
                for (int j = 0; j < 4; ++j) {
                    float2 f = __half22float2(h2[j]);
                    a[2 * j]     = fmaf(f.x, pw, a[2 * j]);
                    a[2 * j + 1] = fmaf(f.y, pw, a[2 * j + 1]);
                }
            }
        } else if (active) {
            const float advh = myh ? adv.y : adv.x;
            for (int i = s0 + slot; i < s1; i += 2) {
                int s = csr_src[i];
                float e = AS[(size_t)s * 2 + myh] + advh;
                e = e > 0.f ? e : NEG_SLOPE * e;
                float pw = __expf(e);
                uint4 hv = *(const uint4*)&H[(size_t)s * 128 + 8 * c];
                const __half2* h2 = (const __half2*)&hv;
#pragma unroll
                for (int j = 0; j < 4; ++j) {
                    float2 f = __half22float2(h2[j]);
                    a[2 * j]     = fmaf(f.x, pw, a[2 * j]);
                    a[2 * j + 1] = fmaf(f.y, pw, a[2 * j + 1]);
                }
            }
        }
        // combine the 2 edge slots (within half)
#pragma unroll
        for (int j = 0; j < 8; ++j) a[j] += __shfl_xor(a[j], 16, 64);
        if (hl < 16 && active) {
            float o[8];
            o[0] = a[0] * myinv + bA.x; o[1] = a[1] * myinv + bA.y;
            o[2] = a[2] * myinv + bA.z; o[3] = a[3] * myinv + bA.w;
            o[4] = a[4] * myinv + bB.x; o[5] = a[5] * myinv + bB.y;
            o[6] = a[6] * myinv + bB.z; o[7] = a[7] * myinv + bB.w;
            if (do_relu) {
#pragma unroll
                for (int j = 0; j < 8; ++j) o[j] = fmaxf(o[j], 0.f);
            }
            __half2 hp[4];
#pragma unroll
            for (int j = 0; j < 4; ++j) hp[j] = __floats2half2_rn(o[2 * j], o[2 * j + 1]);
            *(uint4*)&Out[(size_t)n * 128 + 8 * c] = *(uint4*)hp;
        }
    }
}

// ---------- fused GAT, heads=1, fp16 H, fp32 out. HALF-WAVE per node ----------
__global__ __launch_bounds__(256) void gat_csr1(const int* __restrict__ offs,
                                                const int* __restrict__ csr_src,
                                                const float* __restrict__ AS,
                                                const float* __restrict__ AD,
                                                const __half* __restrict__ H,
                                                const float* __restrict__ bias,
                                                float* __restrict__ Out,
                                                int N, int do_relu) {
    __shared__ int   sS[4][64];
    __shared__ float sP[4][64];
    const int lane = threadIdx.x & 63;
    const int w = threadIdx.x >> 6;
    const int wid = (int)((blockIdx.x * blockDim.x + threadIdx.x) >> 6);
    const int nw = (int)((gridDim.x * blockDim.x) >> 6);
    const int half = lane >> 5;
    const int hl = lane & 31;
    const int c = hl & 15;       // channels 4c..4c+3
    const int slot = hl >> 4;    // 2 edge slots
    const int hbase = half * 32;
    int* const sSw = &sS[w][0];
    float* const sPw = &sP[w][0];
    const float4 b4 = *(const float4*)&bias[4 * c];
    const int npairs = (N + 1) >> 1;

    for (int np = wid; np < npairs; np += nw) {
        const int n = 2 * np + half;
        const bool active = (n < N);
        int s0 = 0, s1 = 0;
        float adv0 = 0.f;
        if (active) { s0 = offs[n]; s1 = offs[n + 1]; adv0 = AD[n]; }
        const int deg = s1 - s0;
        float dn0 = 0.f, p0 = 0.f;
        int sreg = 0;
        for (int i = s0 + hl; i < s1; i += 32) {
            int s = csr_src[i];
            float e0 = AS[s] + adv0;
            e0 = e0 > 0.f ? e0 : NEG_SLOPE * e0;
            float pe0 = __expf(e0);
            dn0 += pe0;
            if (i == s0 + hl) { sreg = s; p0 = pe0; }
        }
        for (int o = 1; o < 32; o <<= 1) dn0 += __shfl_xor(dn0, o, 64);
        const float inv0 = 1.f / (dn0 + EPSF);

        float a[4];
#pragma unroll
        for (int j = 0; j < 4; ++j) a[j] = 0.f;
        if (deg <= 32) {
            sSw[lane] = sreg;
            sPw[lane] = p0;
            const int npc = (deg + 1) >> 1;
            int t = 0;
            for (; t + 8 <= npc; t += 8) {
                int ss[8]; float pw[8]; uint2 hv[8];
#pragma unroll
                for (int k = 0; k < 8; ++k) {
                    int idx = hbase + 2 * (t + k) + slot;
                    ss[k] = sSw[idx];
                    pw[k] = sPw[idx];
                }
#pragma unroll
                for (int k = 0; k < 8; ++k)
                    hv[k] = *(const uint2*)&H[(size_t)ss[k] * 64 + 4 * c];
#pragma unroll
                for (int k = 0; k < 8; ++k) {
                    const __half2* h2 = (const __half2*)&hv[k];
                    float2 f01 = __half22float2(h2[0]);
                    float2 f23 = __half22float2(h2[1]);
                    a[0] = fmaf(f01.x, pw[k], a[0]);
                    a[1] = fmaf(f01.y, pw[k], a[1]);
                    a[2] = fmaf(f23.x, pw[k], a[2]);
                    a[3] = fmaf(f23.y, pw[k], a[3]);
                }
            }
            for (; t < npc; ++t) {
                int idx = hbase + 2 * t + slot;
                int s = sSw[idx];
                float pw = sPw[idx];
                uint2 hv = *(const uint2*)&H[(size_t)s * 64 + 4 * c];
                const __half2* h2 = (const __half2*)&hv;
                float2 f01 = __half22float2(h2[0]);
                float2 f23 = __half22float2(h2[1]);
                a[0] = fmaf(f01.x, pw, a[0]);
                a[1] = fmaf(f01.y, pw, a[1]);
                a[2] = fmaf(f23.x, pw, a[2]);
                a[3] = fmaf(f23.y, pw, a[3]);
            }
        } else if (active) {
            for (int i = s0 + slot; i < s1; i += 2) {
                int s = csr_src[i];
                float e = AS[s] + adv0;
                e = e > 0.f ? e : NEG_SLOPE * e;
                float pw = __expf(e);
                uint2 hv = *(const uint2*)&H[(size_t)s * 64 + 4 * c];
                const __half2* h2 = (const __half2*)&hv;
                float2 f01 = __half22float2(h2[0]);
                float2 f23 = __half22float2(h2[1]);
                a[0] = fmaf(f01.x, pw, a[0]);
                a[1] = fmaf(f01.y, pw, a[1]);
                a[2] = fmaf(f23.x, pw, a[2]);
                a[3] = fmaf(f23.y, pw, a[3]);
            }
        }
#pragma unroll
        for (int j = 0; j < 4; ++j) a[j] += __shfl_xor(a[j], 16, 64);
        if (hl < 16 && active) {
            float4 o;
            o.x = a[0] * inv0 + b4.x;
            o.y = a[1] * inv0 + b4.y;
            o.z = a[2] * inv0 + b4.z;
            o.w = a[3] * inv0 + b4.w;
            if (do_relu) {
                o.x = fmaxf(o.x, 0.f); o.y = fmaxf(o.y, 0.f);
                o.z = fmaxf(o.z, 0.f); o.w = fmaxf(o.w, 0.f);
            }
            *(float4*)&Out[(size_t)n * 64 + 4 * c] = o;
        }
    }
}

extern "C" void kernel_launch(void* const* d_in, const int* in_sizes, int n_in,
                              void* d_out, int out_size, void* d_ws, size_t ws_size,
                              hipStream_t stream) {
    const float* x   = (const float*)d_in[0];
    const int*   ei  = (const int*)d_in[1];
    const float* W0  = (const float*)d_in[2];
    const float* as0 = (const float*)d_in[3];
    const float* ad0 = (const float*)d_in[4];
    const float* b0  = (const float*)d_in[5];
    const float* W1  = (const float*)d_in[6];
    const float* as1 = (const float*)d_in[7];
    const float* ad1 = (const float*)d_in[8];
    const float* b1  = (const float*)d_in[9];
    const float* W2  = (const float*)d_in[10];
    const float* as2 = (const float*)d_in[11];
    const float* ad2 = (const float*)d_in[12];
    const float* b2  = (const float*)d_in[13];

    const int N = in_sizes[0] / 128;
    const int E_raw = in_sizes[1] / 2;
    const int E = E_raw + N;

    char* ws = (char*)d_ws;
    size_t off = 0;
    auto alloc = [&](size_t bytes) {
        void* p = ws + off;
        off = (off + bytes + 255) & ~(size_t)255;
        return p;
    };
    __half* hh    = (__half*)alloc((size_t)N * 128 * 2);
    __half* obufh = (__half*)alloc((size_t)N * 128 * 2);
    float* asb  = (float*)alloc((size_t)N * 2 * 4);
    float* adb  = (float*)alloc((size_t)N * 2 * 4);
    int*   cnt  = (int*)alloc((size_t)(N + 4) * 4);
    int*   offs = (int*)alloc((size_t)(N + 1) * 4);
    int*   bsum = (int*)alloc(1024);
    int* csr_src = (int*)alloc((size_t)E * 4);
    (void)ws_size; (void)n_in; (void)out_size;

    // ---- build CSR grouped by dst (reused by all 3 layers) ----
    const int nb = (N + 255) / 256;
    const int n4 = (N + 3) / 4;
    zero_kernel<<<(n4 + 255) / 256, 256, 0, stream>>>(cnt, n4);
    hist_kernel<<<2048, 256, 0, stream>>>(ei, E_raw, N, cnt);
    scan_block<<<nb, 256, 0, stream>>>(cnt, offs, bsum, N);
    scan_bsum<<<1, 256, 0, stream>>>(bsum, nb);
    scan_add<<<nb, 256, 0, stream>>>(offs, bsum, N, E);
    scatter_edges_part<<<2048, 256, 0, stream>>>(ei, E_raw, N, cnt, offs, csr_src);

    const int gemm_blocks = (N + 63) / 64;
    const int npairs = (N + 1) / 2;
    const int gat_blocks = (npairs * 64 + 255) / 256;  // one wave per node PAIR

    // Layer 0: x (fp32) -> obufh (fp16, relu)
    gemm_fused<128, 2, true, float><<<gemm_blocks, 256, 0, stream>>>(x, W0, as0, ad0, nullptr, hh, asb, adb, N);
    gat_csr2<<<gat_blocks, 256, 0, stream>>>(offs, csr_src, asb, adb, hh, b0, obufh, N, 1);
    // Layer 1: obufh (fp16) -> obufh (fp16, relu)
    gemm_fused<128, 2, true, __half><<<gemm_blocks, 256, 0, stream>>>(obufh, W1, as1, ad1, nullptr, hh, asb, adb, N);
    gat_csr2<<<gat_blocks, 256, 0, stream>>>(offs, csr_src, asb, adb, hh, b1, obufh, N, 1);
    // Layer 2: obufh (fp16) -> d_out (fp32, heads=1, no relu); h stored fp16
    gemm_fused<64, 1, true, __half><<<gemm_blocks, 256, 0, stream>>>(obufh, W2, as2, ad2, nullptr, hh, asb, adb, N);
    gat_csr1<<<gat_blocks, 256, 0, stream>>>(offs, csr_src, asb, adb, hh, b2, (float*)d_out, N, 0);
}

// Round 11
// 289.865 us; speedup vs baseline: 1.0484x; 1.0484x over previous
//
#include <hip/hip_runtime.h>
#include <hip/hip_fp16.h>

#define NEG_SLOPE 0.2f
#define EPSF 1e-16f

// ---------- GEMM + fused alpha epilogue ----------
template<int BN, int HEADS, bool OUTH, typename XT>
__global__ __launch_bounds__(256) void gemm_fused(const XT* __restrict__ X,
                                                  const float* __restrict__ W,
                                                  const float* __restrict__ asrc,
                                                  const float* __restrict__ adst,
                                                  float* __restrict__ OutF,
                                                  __half* __restrict__ OutH,
                                                  float* __restrict__ AS,
                                                  float* __restrict__ AD, int N) {
    constexpr int BM = 64, BK = 32, K = 128;
    constexpr int TN = BN / 16;  // 8 (BN=128) or 4 (BN=64)
    __shared__ float Xs[BM][BK + 4];
    __shared__ float Ws[BK][BN];
    const int tid = threadIdx.x;
    const int tx = tid & 15, ty = tid >> 4;
    const int row0 = blockIdx.x * BM;

    float acc[4][TN];
#pragma unroll
    for (int i = 0; i < 4; ++i)
#pragma unroll
        for (int j = 0; j < TN; ++j) acc[i][j] = 0.f;

    for (int kb = 0; kb < K; kb += BK) {
        __syncthreads();
        for (int idx = tid; idx < BK * (BN / 4); idx += 256) {
            int r = idx / (BN / 4), c4 = idx % (BN / 4);
            ((float4*)&Ws[r][0])[c4] = ((const float4*)&W[(size_t)(kb + r) * BN])[c4];
        }
        for (int t = tid; t < BM * (BK / 4); t += 256) {
            int r = t >> 3, c4 = t & 7;
            int gr = row0 + r;
            float f[4] = {0.f, 0.f, 0.f, 0.f};
            if (gr < N) {
                if constexpr (sizeof(XT) == 2) {
                    uint2 raw = *((const uint2*)&X[(size_t)gr * K + kb + c4 * 4]);
                    const __half2* hp = (const __half2*)&raw;
                    float2 f0 = __half22float2(hp[0]);
                    float2 f1 = __half22float2(hp[1]);
                    f[0] = f0.x; f[1] = f0.y; f[2] = f1.x; f[3] = f1.y;
                } else {
                    float4 v = *((const float4*)&X[(size_t)gr * K + kb + c4 * 4]);
                    f[0] = v.x; f[1] = v.y; f[2] = v.z; f[3] = v.w;
                }
            }
            Xs[r][c4 * 4 + 0] = f[0]; Xs[r][c4 * 4 + 1] = f[1];
            Xs[r][c4 * 4 + 2] = f[2]; Xs[r][c4 * 4 + 3] = f[3];
        }
        __syncthreads();
#pragma unroll
        for (int k = 0; k < BK; ++k) {
            float xr[4];
#pragma unroll
            for (int i = 0; i < 4; ++i) xr[i] = Xs[ty * 4 + i][k];
            float wv[TN];
#pragma unroll
            for (int j4 = 0; j4 < TN / 4; ++j4) {
                float4 w4 = ((float4*)&Ws[k][0])[tx * (TN / 4) + j4];
                wv[j4 * 4 + 0] = w4.x; wv[j4 * 4 + 1] = w4.y;
                wv[j4 * 4 + 2] = w4.z; wv[j4 * 4 + 3] = w4.w;
            }
#pragma unroll
            for (int i = 0; i < 4; ++i)
#pragma unroll
                for (int j = 0; j < TN; ++j) acc[i][j] = fmaf(xr[i], wv[j], acc[i][j]);
        }
    }

    float av[TN], dv[TN];
#pragma unroll
    for (int j = 0; j < TN; ++j) { av[j] = asrc[tx * TN + j]; dv[j] = adst[tx * TN + j]; }

#pragma unroll
    for (int i = 0; i < 4; ++i) {
        int gr = row0 + ty * 4 + i;
        if (gr >= N) continue;
        if (OUTH) {
            __half2 hp[TN / 2];
#pragma unroll
            for (int j2 = 0; j2 < TN / 2; ++j2)
                hp[j2] = __floats2half2_rn(acc[i][j2 * 2], acc[i][j2 * 2 + 1]);
            if (TN == 8)
                *((uint4*)&OutH[(size_t)gr * BN + tx * TN]) = *(uint4*)hp;
            else
                *((uint2*)&OutH[(size_t)gr * BN + tx * TN]) = *(uint2*)hp;
        } else {
#pragma unroll
            for (int j4 = 0; j4 < TN / 4; ++j4) {
                float4 o4 = make_float4(acc[i][j4 * 4 + 0], acc[i][j4 * 4 + 1],
                                        acc[i][j4 * 4 + 2], acc[i][j4 * 4 + 3]);
                *((float4*)&OutF[(size_t)gr * BN + tx * TN + j4 * 4]) = o4;
            }
        }
        float ps = 0.f, pd = 0.f;
#pragma unroll
        for (int j = 0; j < TN; ++j) { ps = fmaf(acc[i][j], av[j], ps); pd = fmaf(acc[i][j], dv[j], pd); }
        if (HEADS == 2) {
            for (int o = 1; o < 8; o <<= 1) { ps += __shfl_xor(ps, o, 64); pd += __shfl_xor(pd, o, 64); }
            if ((tx & 7) == 0) { AS[gr * 2 + (tx >> 3)] = ps; AD[gr * 2 + (tx >> 3)] = pd; }
        } else {
            for (int o = 1; o < 16; o <<= 1) { ps += __shfl_xor(ps, o, 64); pd += __shfl_xor(pd, o, 64); }
            if (tx == 0) { AS[gr] = ps; AD[gr] = pd; }
        }
    }
}

// ---------- CSR build ----------
__global__ void zero_kernel(int* __restrict__ p, int n4) {
    int i = blockIdx.x * blockDim.x + threadIdx.x;
    if (i < n4) ((int4*)p)[i] = make_int4(0, 0, 0, 0);
}

__global__ void hist_kernel(const int* __restrict__ ei, int E_raw, int N,
                            int* __restrict__ cnt) {
    const int E = E_raw + N;
    for (int e = blockIdx.x * blockDim.x + threadIdx.x; e < E; e += gridDim.x * blockDim.x) {
        int d = (e < E_raw) ? ei[E_raw + e] : e - E_raw;
        atomicAdd(&cnt[d], 1);
    }
}

__global__ __launch_bounds__(256) void scan_block(const int* __restrict__ cnt,
                                                  int* __restrict__ offs,
                                                  int* __restrict__ bsum, int N) {
    __shared__ int wsum[4];
    const int i = blockIdx.x * 256 + threadIdx.x;
    const int lane = threadIdx.x & 63, w = threadIdx.x >> 6;
    int v = (i < N) ? cnt[i] : 0;
    int incl = v;
    for (int o = 1; o < 64; o <<= 1) {
        int t = __shfl_up(incl, o, 64);
        if (lane >= o) incl += t;
    }
    if (lane == 63) wsum[w] = incl;
    __syncthreads();
    int prefix = 0;
    for (int k = 0; k < w; ++k) prefix += wsum[k];
    if (i < N) offs[i] = prefix + incl - v;
    if (threadIdx.x == 255) bsum[blockIdx.x] = prefix + incl;
}

__global__ __launch_bounds__(256) void scan_bsum(int* __restrict__ bsum, int nb) {
    __shared__ int wsum[4];
    const int lane = threadIdx.x & 63, w = threadIdx.x >> 6;
    int v = (threadIdx.x < nb) ? bsum[threadIdx.x] : 0;
    int incl = v;
    for (int o = 1; o < 64; o <<= 1) {
        int t = __shfl_up(incl, o, 64);
        if (lane >= o) incl += t;
    }
    if (lane == 63) wsum[w] = incl;
    __syncthreads();
    int prefix = 0;
    for (int k = 0; k < w; ++k) prefix += wsum[k];
    if (threadIdx.x < nb) bsum[threadIdx.x] = prefix + incl - v;
}

__global__ void scan_add(int* __restrict__ offs, const int* __restrict__ bsum,
                         int N, int E) {
    const int i = blockIdx.x * 256 + threadIdx.x;
    if (i < N) offs[i] += bsum[blockIdx.x];
    if (i == 0) offs[N] = E;
}

// XCD-partitioned scatter (R5). pos = offs[d] + (--cnt[d]); cnt ends at 0.
__global__ void scatter_edges_part(const int* __restrict__ ei, int E_raw, int N,
                                   int* __restrict__ cnt,
                                   const int* __restrict__ offs,
                                   int* __restrict__ csr_src) {
    const int NPART = 8;
    const int part = blockIdx.x & (NPART - 1);
    const int gblocks = gridDim.x >> 3;
    const int grank = blockIdx.x >> 3;
    const int tid = grank * blockDim.x + threadIdx.x;
    const int nthr = gblocks * blockDim.x;
    const int E = E_raw + N;
    const int dlo = (int)(((long long)N * part) / NPART);
    const int dhi = (int)(((long long)N * (part + 1)) / NPART);
    for (int e = tid; e < E; e += nthr) {
        int d = (e < E_raw) ? ei[E_raw + e] : e - E_raw;
        if (d >= dlo && d < dhi) {
            int s = (e < E_raw) ? ei[e] : d;
            int old = atomicSub(&cnt[d], 1);
            csr_src[offs[d] + old - 1] = s;
        }
    }
}

// ---------- fused GAT per-dst, heads=2, fp16 H, fp16 out (R9 structure) ----------
// Wave per node; 4 edge slots x 16 lanes x 8ch (uint4). NEW: the first
// 16-edge batch's H loads are issued BEFORE the denom pass (indices read
// directly from csr_src, min-clamped), so gather latency overlaps the
// AS-gather/exp/reduce phase. Phantom edges get weight 0 from LDS.
__global__ __launch_bounds__(256) void gat_csr2(const int* __restrict__ offs,
                                                const int* __restrict__ csr_src,
                                                const float* __restrict__ AS,
                                                const float* __restrict__ AD,
                                                const __half* __restrict__ H,
                                                const float* __restrict__ bias,
                                                __half* __restrict__ Out,
                                                int N, int do_relu) {
    __shared__ int   sS[4][64];
    __shared__ float sP0[4][64];
    __shared__ float sP1[4][64];
    const int lane = threadIdx.x & 63;
    const int w = threadIdx.x >> 6;
    const int wid = (int)((blockIdx.x * blockDim.x + threadIdx.x) >> 6);
    const int nw = (int)((gridDim.x * blockDim.x) >> 6);
    const int c = lane & 15;      // channels 8c..8c+7
    const int slot = lane >> 4;   // 4 edge slots
    const int myh = c >> 3;       // head owning my channels
    int* const sSw = &sS[w][0];
    const float* const myp = myh ? &sP1[w][0] : &sP0[w][0];
    const float4 bA = *(const float4*)&bias[8 * c];
    const float4 bB = *(const float4*)&bias[8 * c + 4];

    for (int n = wid; n < N; n += nw) {
        const int s0 = offs[n], s1 = offs[n + 1];
        const int deg = s1 - s0;
        const float2 adv = *(const float2*)&AD[(size_t)n * 2];
        const bool small = (deg <= 64);

        // ---- Phase A: prefetch first 16 edges' H rows (overlap with denom) ----
        uint4 hvA[4];
        if (small) {
            int ssA[4];
#pragma unroll
            for (int k = 0; k < 4; ++k) {
                int i = s0 + 4 * k + slot;
                i = i < s1 ? i : s1 - 1;      // clamp: always a valid edge
                ssA[k] = csr_src[i];
            }
#pragma unroll
            for (int k = 0; k < 4; ++k)
                hvA[k] = *(const uint4*)&H[(size_t)ssA[k] * 128 + 8 * c];
        }

        // ---- Phase B: denom pass ----
        float dn0 = 0.f, dn1 = 0.f, p0 = 0.f, p1 = 0.f;
        int sreg = 0;
        for (int i = s0 + lane; i < s1; i += 64) {
            int s = csr_src[i];
            float2 a2 = *(const float2*)&AS[(size_t)s * 2];
            float e0 = a2.x + adv.x, e1 = a2.y + adv.y;
            e0 = e0 > 0.f ? e0 : NEG_SLOPE * e0;
            e1 = e1 > 0.f ? e1 : NEG_SLOPE * e1;
            float pe0 = __expf(e0), pe1 = __expf(e1);
            dn0 += pe0; dn1 += pe1;
            if (i == s0 + lane) { sreg = s; p0 = pe0; p1 = pe1; }
        }
        for (int o = 1; o < 64; o <<= 1) {
            dn0 += __shfl_xor(dn0, o, 64);
            dn1 += __shfl_xor(dn1, o, 64);
        }
        const float myinv = 1.f / ((myh ? dn1 : dn0) + EPSF);

        float a[8];
#pragma unroll
        for (int j = 0; j < 8; ++j) a[j] = 0.f;
        if (small) {
            sSw[lane] = sreg;       // phantom lanes: s=0, p=0
            sP0[w][lane] = p0;
            sP1[w][lane] = p1;
            // ---- Phase C: FMA the prefetched batch (edges 0..15) ----
#pragma unroll
            for (int k = 0; k < 4; ++k) {
                float pw = myp[4 * k + slot];
                const __half2* h2 = (const __half2*)&hvA[k];
#pragma unroll
                for (int j = 0; j < 4; ++j) {
                    float2 f = __half22float2(h2[j]);
                    a[2 * j]     = fmaf(f.x, pw, a[2 * j]);
                    a[2 * j + 1] = fmaf(f.y, pw, a[2 * j + 1]);
                }
            }
            // ---- Phase D: remaining quads (deg > 16) ----
            const int npc = (deg + 3) >> 2;
            int t = 4;
            for (; t + 4 <= npc; t += 4) {
                int ss[4]; float pw[4]; uint4 hv[4];
#pragma unroll
                for (int k = 0; k < 4; ++k) {
                    int idx = 4 * (t + k) + slot;
                    ss[k] = sSw[idx];
                    pw[k] = myp[idx];
                }
#pragma unroll
                for (int k = 0; k < 4; ++k)
                    hv[k] = *(const uint4*)&H[(size_t)ss[k] * 128 + 8 * c];
#pragma unroll
                for (int k = 0; k < 4; ++k) {
                    const __half2* h2 = (const __half2*)&hv[k];
#pragma unroll
                    for (int j = 0; j < 4; ++j) {
                        float2 f = __half22float2(h2[j]);
                        a[2 * j]     = fmaf(f.x, pw[k], a[2 * j]);
                        a[2 * j + 1] = fmaf(f.y, pw[k], a[2 * j + 1]);
                    }
                }
            }
            for (; t < npc; ++t) {
                int idx = 4 * t + slot;
                int s = sSw[idx];
                float pw = myp[idx];
                uint4 hv = *(const uint4*)&H[(size_t)s * 128 + 8 * c];
                const __half2* h2 = (const __half2*)&hv;
#pragma unroll
                for (int j = 0; j < 4; ++j) {
                    float2 f = __half22float2(h2[j]);
                    a[2 * j]     = fmaf(f.x, pw, a[2 * j]);
                    a[2 * j + 1] = fmaf(f.y, pw, a[2 * j + 1]);
                }
            }
        } else {
            const float advh = myh ? adv.y : adv.x;
            for (int i = s0 + slot; i < s1; i += 4) {
                int s = csr_src[i];
                float e = AS[(size_t)s * 2 + myh] + advh;
                e = e > 0.f ? e : NEG_SLOPE * e;
                float pw = __expf(e);
                uint4 hv = *(const uint4*)&H[(size_t)s * 128 + 8 * c];
                const __half2* h2 = (const __half2*)&hv;
#pragma unroll
                for (int j = 0; j < 4; ++j) {
                    float2 f = __half22float2(h2[j]);
                    a[2 * j]     = fmaf(f.x, pw, a[2 * j]);
                    a[2 * j + 1] = fmaf(f.y, pw, a[2 * j + 1]);
                }
            }
        }
#pragma unroll
        for (int j = 0; j < 8; ++j) {
            a[j] += __shfl_xor(a[j], 16, 64);
            a[j] += __shfl_xor(a[j], 32, 64);
        }
        if (lane < 16) {
            float o[8];
            o[0] = a[0] * myinv + bA.x; o[1] = a[1] * myinv + bA.y;
            o[2] = a[2] * myinv + bA.z; o[3] = a[3] * myinv + bA.w;
            o[4] = a[4] * myinv + bB.x; o[5] = a[5] * myinv + bB.y;
            o[6] = a[6] * myinv + bB.z; o[7] = a[7] * myinv + bB.w;
            if (do_relu) {
#pragma unroll
                for (int j = 0; j < 8; ++j) o[j] = fmaxf(o[j], 0.f);
            }
            __half2 hp[4];
#pragma unroll
            for (int j = 0; j < 4; ++j) hp[j] = __floats2half2_rn(o[2 * j], o[2 * j + 1]);
            *(uint4*)&Out[(size_t)n * 128 + 8 * c] = *(uint4*)hp;
        }
    }
}

// ---------- fused GAT per-dst, heads=1, fp16 H, fp32 out (R9 + prefetch) ----------
__global__ __launch_bounds__(256) void gat_csr1(const int* __restrict__ offs,
                                                const int* __restrict__ csr_src,
                                                const float* __restrict__ AS,
                                                const float* __restrict__ AD,
                                                const __half* __restrict__ H,
                                                const float* __restrict__ bias,
                                                float* __restrict__ Out,
                                                int N, int do_relu) {
    __shared__ int   sS[4][64];
    __shared__ float sP[4][64];
    const int lane = threadIdx.x & 63;
    const int w = threadIdx.x >> 6;
    const int wid = (int)((blockIdx.x * blockDim.x + threadIdx.x) >> 6);
    const int nw = (int)((gridDim.x * blockDim.x) >> 6);
    const int c = lane & 15;     // channels 4c..4c+3
    const int slot = lane >> 4;  // 4 edge slots
    int* const sSw = &sS[w][0];
    float* const sPw = &sP[w][0];
    const float4 b4 = *(const float4*)&bias[4 * c];

    for (int n = wid; n < N; n += nw) {
        const int s0 = offs[n], s1 = offs[n + 1];
        const int deg = s1 - s0;
        const float adv0 = AD[n];
        const bool small = (deg <= 64);

        // Phase A: prefetch first 16 edges' H rows
        uint2 hvA[4];
        if (small) {
            int ssA[4];
#pragma unroll
            for (int k = 0; k < 4; ++k) {
                int i = s0 + 4 * k + slot;
                i = i < s1 ? i : s1 - 1;
                ssA[k] = csr_src[i];
            }
#pragma unroll
            for (int k = 0; k < 4; ++k)
                hvA[k] = *(const uint2*)&H[(size_t)ssA[k] * 64 + 4 * c];
        }

        float dn0 = 0.f, p0 = 0.f;
        int sreg = 0;
        for (int i = s0 + lane; i < s1; i += 64) {
            int s = csr_src[i];
            float e0 = AS[s] + adv0;
            e0 = e0 > 0.f ? e0 : NEG_SLOPE * e0;
            float pe0 = __expf(e0);
            dn0 += pe0;
            if (i == s0 + lane) { sreg = s; p0 = pe0; }
        }
        for (int o = 1; o < 64; o <<= 1) dn0 += __shfl_xor(dn0, o, 64);
        const float inv0 = 1.f / (dn0 + EPSF);

        float a[4];
#pragma unroll
        for (int j = 0; j < 4; ++j) a[j] = 0.f;
        if (small) {
            sSw[lane] = sreg;
            sPw[lane] = p0;
            // Phase C: prefetched batch
#pragma unroll
            for (int k = 0; k < 4; ++k) {
                float pw = sPw[4 * k + slot];
                const __half2* h2 = (const __half2*)&hvA[k];
                float2 f01 = __half22float2(h2[0]);
                float2 f23 = __half22float2(h2[1]);
                a[0] = fmaf(f01.x, pw, a[0]);
                a[1] = fmaf(f01.y, pw, a[1]);
                a[2] = fmaf(f23.x, pw, a[2]);
                a[3] = fmaf(f23.y, pw, a[3]);
            }
            // Phase D: remaining quads
            const int npc = (deg + 3) >> 2;
            int t = 4;
            for (; t + 4 <= npc; t += 4) {
                int ss[4]; float pw[4]; uint2 hv[4];
#pragma unroll
                for (int k = 0; k < 4; ++k) {
                    int idx = 4 * (t + k) + slot;
                    ss[k] = sSw[idx];
                    pw[k] = sPw[idx];
                }
#pragma unroll
                for (int k = 0; k < 4; ++k)
                    hv[k] = *(const uint2*)&H[(size_t)ss[k] * 64 + 4 * c];
#pragma unroll
                for (int k = 0; k < 4; ++k) {
                    const __half2* h2 = (const __half2*)&hv[k];
                    float2 f01 = __half22float2(h2[0]);
                    float2 f23 = __half22float2(h2[1]);
                    a[0] = fmaf(f01.x, pw[k], a[0]);
                    a[1] = fmaf(f01.y, pw[k], a[1]);
                    a[2] = fmaf(f23.x, pw[k], a[2]);
                    a[3] = fmaf(f23.y, pw[k], a[3]);
                }
            }
            for (; t < npc; ++t) {
                int idx = 4 * t + slot;
                int s = sSw[idx];
                float pw = sPw[idx];
                uint2 hv = *(const uint2*)&H[(size_t)s * 64 + 4 * c];
                const __half2* h2 = (const __half2*)&hv;
                float2 f01 = __half22float2(h2[0]);
                float2 f23 = __half22float2(h2[1]);
                a[0] = fmaf(f01.x, pw, a[0]);
                a[1] = fmaf(f01.y, pw, a[1]);
                a[2] = fmaf(f23.x, pw, a[2]);
                a[3] = fmaf(f23.y, pw, a[3]);
            }
        } else {
            for (int i = s0 + slot; i < s1; i += 4) {
                int s = csr_src[i];
                float e = AS[s] + adv0;
                e = e > 0.f ? e : NEG_SLOPE * e;
                float pw = __expf(e);
                uint2 hv = *(const uint2*)&H[(size_t)s * 64 + 4 * c];
                const __half2* h2 = (const __half2*)&hv;
                float2 f01 = __half22float2(h2[0]);
                float2 f23 = __half22float2(h2[1]);
                a[0] = fmaf(f01.x, pw, a[0]);
                a[1] = fmaf(f01.y, pw, a[1]);
                a[2] = fmaf(f23.x, pw, a[2]);
                a[3] = fmaf(f23.y, pw, a[3]);
            }
        }
#pragma unroll
        for (int j = 0; j < 4; ++j) {
            a[j] += __shfl_xor(a[j], 16, 64);
            a[j] += __shfl_xor(a[j], 32, 64);
        }
        if (lane < 16) {
            float4 o;
            o.x = a[0] * inv0 + b4.x;
            o.y = a[1] * inv0 + b4.y;
            o.z = a[2] * inv0 + b4.z;
            o.w = a[3] * inv0 + b4.w;
            if (do_relu) {
                o.x = fmaxf(o.x, 0.f); o.y = fmaxf(o.y, 0.f);
                o.z = fmaxf(o.z, 0.f); o.w = fmaxf(o.w, 0.f);
            }
            *(float4*)&Out[(size_t)n * 64 + 4 * c] = o;
        }
    }
}

extern "C" void kernel_launch(void* const* d_in, const int* in_sizes, int n_in,
                              void* d_out, int out_size, void* d_ws, size_t ws_size,
                              hipStream_t stream) {
    const float* x   = (const float*)d_in[0];
    const int*   ei  = (const int*)d_in[1];
    const float* W0  = (const float*)d_in[2];
    const float* as0 = (const float*)d_in[3];
    const float* ad0 = (const float*)d_in[4];
    const float* b0  = (const float*)d_in[5];
    const float* W1  = (const float*)d_in[6];
    const float* as1 = (const float*)d_in[7];
    const float* ad1 = (const float*)d_in[8];
    const float* b1  = (const float*)d_in[9];
    const float* W2  = (const float*)d_in[10];
    const float* as2 = (const float*)d_in[11];
    const float* ad2 = (const float*)d_in[12];
    const float* b2  = (const float*)d_in[13];

    const int N = in_sizes[0] / 128;
    const int E_raw = in_sizes[1] / 2;
    const int E = E_raw + N;

    char* ws = (char*)d_ws;
    size_t off = 0;
    auto alloc = [&](size_t bytes) {
        void* p = ws + off;
        off = (off + bytes + 255) & ~(size_t)255;
        return p;
    };
    __half* hh    = (__half*)alloc((size_t)N * 128 * 2);
    __half* obufh = (__half*)alloc((size_t)N * 128 * 2);
    float* asb  = (float*)alloc((size_t)N * 2 * 4);
    float* adb  = (float*)alloc((size_t)N * 2 * 4);
    int*   cnt  = (int*)alloc((size_t)(N + 4) * 4);
    int*   offs = (int*)alloc((size_t)(N + 1) * 4);
    int*   bsum = (int*)alloc(1024);
    int* csr_src = (int*)alloc((size_t)E * 4);
    (void)ws_size; (void)n_in; (void)out_size;

    // ---- build CSR grouped by dst (reused by all 3 layers) ----
    const int nb = (N + 255) / 256;
    const int n4 = (N + 3) / 4;
    zero_kernel<<<(n4 + 255) / 256, 256, 0, stream>>>(cnt, n4);
    hist_kernel<<<2048, 256, 0, stream>>>(ei, E_raw, N, cnt);
    scan_block<<<nb, 256, 0, stream>>>(cnt, offs, bsum, N);
    scan_bsum<<<1, 256, 0, stream>>>(bsum, nb);
    scan_add<<<nb, 256, 0, stream>>>(offs, bsum, N, E);
    scatter_edges_part<<<2048, 256, 0, stream>>>(ei, E_raw, N, cnt, offs, csr_src);

    const int gemm_blocks = (N + 63) / 64;
    const int gat_blocks = (N * 64 + 255) / 256;  // one full wave per node (R9)

    // Layer 0: x (fp32) -> obufh (fp16, relu)
    gemm_fused<128, 2, true, float><<<gemm_blocks, 256, 0, stream>>>(x, W0, as0, ad0, nullptr, hh, asb, adb, N);
    gat_csr2<<<gat_blocks, 256, 0, stream>>>(offs, csr_src, asb, adb, hh, b0, obufh, N, 1);
    // Layer 1: obufh (fp16) -> obufh (fp16, relu)
    gemm_fused<128, 2, true, __half><<<gemm_blocks, 256, 0, stream>>>(obufh, W1, as1, ad1, nullptr, hh, asb, adb, N);
    gat_csr2<<<gat_blocks, 256, 0, stream>>>(offs, csr_src, asb, adb, hh, b1, obufh, N, 1);
    // Layer 2: obufh (fp16) -> d_out (fp32, heads=1, no relu); h stored fp16
    gemm_fused<64, 1, true, __half><<<gemm_blocks, 256, 0, stream>>>(obufh, W2, as2, ad2, nullptr, hh, asb, adb, N);
    gat_csr1<<<gat_blocks, 256, 0, stream>>>(offs, csr_src, asb, adb, hh, b2, (float*)d_out, N, 0);
}

// Round 12
// 275.226 us; speedup vs baseline: 1.1042x; 1.0532x over previous
//
#include <hip/hip_runtime.h>
#include <hip/hip_fp16.h>

#define NEG_SLOPE 0.2f
#define EPSF 1e-16f

// ---------- GEMM + fused alpha epilogue ----------
template<int BN, int HEADS, bool OUTH, typename XT>
__global__ __launch_bounds__(256) void gemm_fused(const XT* __restrict__ X,
                                                  const float* __restrict__ W,
                                                  const float* __restrict__ asrc,
                                                  const float* __restrict__ adst,
                                                  float* __restrict__ OutF,
                                                  __half* __restrict__ OutH,
                                                  float* __restrict__ AS,
                                                  float* __restrict__ AD, int N) {
    constexpr int BM = 64, BK = 32, K = 128;
    constexpr int TN = BN / 16;  // 8 (BN=128) or 4 (BN=64)
    __shared__ float Xs[BM][BK + 4];
    __shared__ float Ws[BK][BN];
    const int tid = threadIdx.x;
    const int tx = tid & 15, ty = tid >> 4;
    const int row0 = blockIdx.x * BM;

    float acc[4][TN];
#pragma unroll
    for (int i = 0; i < 4; ++i)
#pragma unroll
        for (int j = 0; j < TN; ++j) acc[i][j] = 0.f;

    for (int kb = 0; kb < K; kb += BK) {
        __syncthreads();
        for (int idx = tid; idx < BK * (BN / 4); idx += 256) {
            int r = idx / (BN / 4), c4 = idx % (BN / 4);
            ((float4*)&Ws[r][0])[c4] = ((const float4*)&W[(size_t)(kb + r) * BN])[c4];
        }
        for (int t = tid; t < BM * (BK / 4); t += 256) {
            int r = t >> 3, c4 = t & 7;
            int gr = row0 + r;
            float f[4] = {0.f, 0.f, 0.f, 0.f};
            if (gr < N) {
                if constexpr (sizeof(XT) == 2) {
                    uint2 raw = *((const uint2*)&X[(size_t)gr * K + kb + c4 * 4]);
                    const __half2* hp = (const __half2*)&raw;
                    float2 f0 = __half22float2(hp[0]);
                    float2 f1 = __half22float2(hp[1]);
                    f[0] = f0.x; f[1] = f0.y; f[2] = f1.x; f[3] = f1.y;
                } else {
                    float4 v = *((const float4*)&X[(size_t)gr * K + kb + c4 * 4]);
                    f[0] = v.x; f[1] = v.y; f[2] = v.z; f[3] = v.w;
                }
            }
            Xs[r][c4 * 4 + 0] = f[0]; Xs[r][c4 * 4 + 1] = f[1];
            Xs[r][c4 * 4 + 2] = f[2]; Xs[r][c4 * 4 + 3] = f[3];
        }
        __syncthreads();
#pragma unroll
        for (int k = 0; k < BK; ++k) {
            float xr[4];
#pragma unroll
            for (int i = 0; i < 4; ++i) xr[i] = Xs[ty * 4 + i][k];
            float wv[TN];
#pragma unroll
            for (int j4 = 0; j4 < TN / 4; ++j4) {
                float4 w4 = ((float4*)&Ws[k][0])[tx * (TN / 4) + j4];
                wv[j4 * 4 + 0] = w4.x; wv[j4 * 4 + 1] = w4.y;
                wv[j4 * 4 + 2] = w4.z; wv[j4 * 4 + 3] = w4.w;
            }
#pragma unroll
            for (int i = 0; i < 4; ++i)
#pragma unroll
                for (int j = 0; j < TN; ++j) acc[i][j] = fmaf(xr[i], wv[j], acc[i][j]);
        }
    }

    float av[TN], dv[TN];
#pragma unroll
    for (int j = 0; j < TN; ++j) { av[j] = asrc[tx * TN + j]; dv[j] = adst[tx * TN + j]; }

#pragma unroll
    for (int i = 0; i < 4; ++i) {
        int gr = row0 + ty * 4 + i;
        if (gr >= N) continue;
        if (OUTH) {
            __half2 hp[TN / 2];
#pragma unroll
            for (int j2 = 0; j2 < TN / 2; ++j2)
                hp[j2] = __floats2half2_rn(acc[i][j2 * 2], acc[i][j2 * 2 + 1]);
            if (TN == 8)
                *((uint4*)&OutH[(size_t)gr * BN + tx * TN]) = *(uint4*)hp;
            else
                *((uint2*)&OutH[(size_t)gr * BN + tx * TN]) = *(uint2*)hp;
        } else {
#pragma unroll
            for (int j4 = 0; j4 < TN / 4; ++j4) {
                float4 o4 = make_float4(acc[i][j4 * 4 + 0], acc[i][j4 * 4 + 1],
                                        acc[i][j4 * 4 + 2], acc[i][j4 * 4 + 3]);
                *((float4*)&OutF[(size_t)gr * BN + tx * TN + j4 * 4]) = o4;
            }
        }
        float ps = 0.f, pd = 0.f;
#pragma unroll
        for (int j = 0; j < TN; ++j) { ps = fmaf(acc[i][j], av[j], ps); pd = fmaf(acc[i][j], dv[j], pd); }
        if (HEADS == 2) {
            for (int o = 1; o < 8; o <<= 1) { ps += __shfl_xor(ps, o, 64); pd += __shfl_xor(pd, o, 64); }
            if ((tx & 7) == 0) { AS[gr * 2 + (tx >> 3)] = ps; AD[gr * 2 + (tx >> 3)] = pd; }
        } else {
            for (int o = 1; o < 16; o <<= 1) { ps += __shfl_xor(ps, o, 64); pd += __shfl_xor(pd, o, 64); }
            if (tx == 0) { AS[gr] = ps; AD[gr] = pd; }
        }
    }
}

// ---------- CSR build ----------
__global__ void zero_kernel(int* __restrict__ p, int n4) {
    int i = blockIdx.x * blockDim.x + threadIdx.x;
    if (i < n4) ((int4*)p)[i] = make_int4(0, 0, 0, 0);
}

__global__ void hist_kernel(const int* __restrict__ ei, int E_raw, int N,
                            int* __restrict__ cnt) {
    const int E = E_raw + N;
    for (int e = blockIdx.x * blockDim.x + threadIdx.x; e < E; e += gridDim.x * blockDim.x) {
        int d = (e < E_raw) ? ei[E_raw + e] : e - E_raw;
        atomicAdd(&cnt[d], 1);
    }
}

__global__ __launch_bounds__(256) void scan_block(const int* __restrict__ cnt,
                                                  int* __restrict__ offs,
                                                  int* __restrict__ bsum, int N) {
    __shared__ int wsum[4];
    const int i = blockIdx.x * 256 + threadIdx.x;
    const int lane = threadIdx.x & 63, w = threadIdx.x >> 6;
    int v = (i < N) ? cnt[i] : 0;
    int incl = v;
    for (int o = 1; o < 64; o <<= 1) {
        int t = __shfl_up(incl, o, 64);
        if (lane >= o) incl += t;
    }
    if (lane == 63) wsum[w] = incl;
    __syncthreads();
    int prefix = 0;
    for (int k = 0; k < w; ++k) prefix += wsum[k];
    if (i < N) offs[i] = prefix + incl - v;
    if (threadIdx.x == 255) bsum[blockIdx.x] = prefix + incl;
}

__global__ __launch_bounds__(256) void scan_bsum(int* __restrict__ bsum, int nb) {
    __shared__ int wsum[4];
    const int lane = threadIdx.x & 63, w = threadIdx.x >> 6;
    int v = (threadIdx.x < nb) ? bsum[threadIdx.x] : 0;
    int incl = v;
    for (int o = 1; o < 64; o <<= 1) {
        int t = __shfl_up(incl, o, 64);
        if (lane >= o) incl += t;
    }
    if (lane == 63) wsum[w] = incl;
    __syncthreads();
    int prefix = 0;
    for (int k = 0; k < w; ++k) prefix += wsum[k];
    if (threadIdx.x < nb) bsum[threadIdx.x] = prefix + incl - v;
}

__global__ void scan_add(int* __restrict__ offs, const int* __restrict__ bsum,
                         int N, int E) {
    const int i = blockIdx.x * 256 + threadIdx.x;
    if (i < N) offs[i] += bsum[blockIdx.x];
    if (i == 0) offs[N] = E;
}

// XCD-partitioned scatter (R5). pos = offs[d] + (--cnt[d]); cnt ends at 0.
__global__ void scatter_edges_part(const int* __restrict__ ei, int E_raw, int N,
                                   int* __restrict__ cnt,
                                   const int* __restrict__ offs,
                                   int* __restrict__ csr_src) {
    const int NPART = 8;
    const int part = blockIdx.x & (NPART - 1);
    const int gblocks = gridDim.x >> 3;
    const int grank = blockIdx.x >> 3;
    const int tid = grank * blockDim.x + threadIdx.x;
    const int nthr = gblocks * blockDim.x;
    const int E = E_raw + N;
    const int dlo = (int)(((long long)N * part) / NPART);
    const int dhi = (int)(((long long)N * (part + 1)) / NPART);
    for (int e = tid; e < E; e += nthr) {
        int d = (e < E_raw) ? ei[E_raw + e] : e - E_raw;
        if (d >= dlo && d < dhi) {
            int s = (e < E_raw) ? ei[e] : d;
            int old = atomicSub(&cnt[d], 1);
            csr_src[offs[d] + old - 1] = s;
        }
    }
}

// ---------- fused GAT per-dst, heads=2, fp16 H, fp16 out (R9 structure) ----------
// Wave per node, GRID-STRIDE over ~6 nodes/wave (grid capped at 2048 blocks
// to avoid block churn + per-block straggler waste -- R11 diagnosis).
__global__ __launch_bounds__(256) void gat_csr2(const int* __restrict__ offs,
                                                const int* __restrict__ csr_src,
                                                const float* __restrict__ AS,
                                                const float* __restrict__ AD,
                                                const __half* __restrict__ H,
                                                const float* __restrict__ bias,
                                                __half* __restrict__ Out,
                                                int N, int do_relu) {
    __shared__ int   sS[4][64];
    __shared__ float sP0[4][64];
    __shared__ float sP1[4][64];
    const int lane = threadIdx.x & 63;
    const int w = threadIdx.x >> 6;
    const int wid = (int)((blockIdx.x * blockDim.x + threadIdx.x) >> 6);
    const int nw = (int)((gridDim.x * blockDim.x) >> 6);
    const int c = lane & 15;      // channels 8c..8c+7
    const int slot = lane >> 4;   // 4 edge slots
    const int myh = c >> 3;       // head owning my channels
    int* const sSw = &sS[w][0];
    const float* const myp = myh ? &sP1[w][0] : &sP0[w][0];
    const float4 bA = *(const float4*)&bias[8 * c];
    const float4 bB = *(const float4*)&bias[8 * c + 4];

    for (int n = wid; n < N; n += nw) {
        const int s0 = offs[n], s1 = offs[n + 1];
        const int deg = s1 - s0;
        const float2 adv = *(const float2*)&AD[(size_t)n * 2];
        float dn0 = 0.f, dn1 = 0.f, p0 = 0.f, p1 = 0.f;
        int sreg = 0;
        for (int i = s0 + lane; i < s1; i += 64) {
            int s = csr_src[i];
            float2 a2 = *(const float2*)&AS[(size_t)s * 2];
            float e0 = a2.x + adv.x, e1 = a2.y + adv.y;
            e0 = e0 > 0.f ? e0 : NEG_SLOPE * e0;
            e1 = e1 > 0.f ? e1 : NEG_SLOPE * e1;
            float pe0 = __expf(e0), pe1 = __expf(e1);
            dn0 += pe0; dn1 += pe1;
            if (i == s0 + lane) { sreg = s; p0 = pe0; p1 = pe1; }
        }
        for (int o = 1; o < 64; o <<= 1) {
            dn0 += __shfl_xor(dn0, o, 64);
            dn1 += __shfl_xor(dn1, o, 64);
        }
        const float myinv = 1.f / ((myh ? dn1 : dn0) + EPSF);

        float a[8];
#pragma unroll
        for (int j = 0; j < 8; ++j) a[j] = 0.f;
        if (deg <= 64) {
            sSw[lane] = sreg;       // phantom lanes: s=0, p=0
            sP0[w][lane] = p0;
            sP1[w][lane] = p1;
            const int npc = (deg + 3) >> 2;   // quads; phantom edges have p=0
            int t = 0;
            for (; t + 4 <= npc; t += 4) {
                int ss[4]; float pw[4]; uint4 hv[4];
#pragma unroll
                for (int k = 0; k < 4; ++k) {
                    int idx = 4 * (t + k) + slot;
                    ss[k] = sSw[idx];
                    pw[k] = myp[idx];
                }
#pragma unroll
                for (int k = 0; k < 4; ++k)
                    hv[k] = *(const uint4*)&H[(size_t)ss[k] * 128 + 8 * c];
#pragma unroll
                for (int k = 0; k < 4; ++k) {
                    const __half2* h2 = (const __half2*)&hv[k];
#pragma unroll
                    for (int j = 0; j < 4; ++j) {
                        float2 f = __half22float2(h2[j]);
                        a[2 * j]     = fmaf(f.x, pw[k], a[2 * j]);
                        a[2 * j + 1] = fmaf(f.y, pw[k], a[2 * j + 1]);
                    }
                }
            }
            for (; t < npc; ++t) {
                int idx = 4 * t + slot;
                int s = sSw[idx];
                float pw = myp[idx];
                uint4 hv = *(const uint4*)&H[(size_t)s * 128 + 8 * c];
                const __half2* h2 = (const __half2*)&hv;
#pragma unroll
                for (int j = 0; j < 4; ++j) {
                    float2 f = __half22float2(h2[j]);
                    a[2 * j]     = fmaf(f.x, pw, a[2 * j]);
                    a[2 * j + 1] = fmaf(f.y, pw, a[2 * j + 1]);
                }
            }
        } else {
            const float advh = myh ? adv.y : adv.x;
            for (int i = s0 + slot; i < s1; i += 4) {
                int s = csr_src[i];
                float e = AS[(size_t)s * 2 + myh] + advh;
                e = e > 0.f ? e : NEG_SLOPE * e;
                float pw = __expf(e);
                uint4 hv = *(const uint4*)&H[(size_t)s * 128 + 8 * c];
                const __half2* h2 = (const __half2*)&hv;
#pragma unroll
                for (int j = 0; j < 4; ++j) {
                    float2 f = __half22float2(h2[j]);
                    a[2 * j]     = fmaf(f.x, pw, a[2 * j]);
                    a[2 * j + 1] = fmaf(f.y, pw, a[2 * j + 1]);
                }
            }
        }
#pragma unroll
        for (int j = 0; j < 8; ++j) {
            a[j] += __shfl_xor(a[j], 16, 64);
            a[j] += __shfl_xor(a[j], 32, 64);
        }
        if (lane < 16) {
            float o[8];
            o[0] = a[0] * myinv + bA.x; o[1] = a[1] * myinv + bA.y;
            o[2] = a[2] * myinv + bA.z; o[3] = a[3] * myinv + bA.w;
            o[4] = a[4] * myinv + bB.x; o[5] = a[5] * myinv + bB.y;
            o[6] = a[6] * myinv + bB.z; o[7] = a[7] * myinv + bB.w;
            if (do_relu) {
#pragma unroll
                for (int j = 0; j < 8; ++j) o[j] = fmaxf(o[j], 0.f);
            }
            __half2 hp[4];
#pragma unroll
            for (int j = 0; j < 4; ++j) hp[j] = __floats2half2_rn(o[2 * j], o[2 * j + 1]);
            *(uint4*)&Out[(size_t)n * 128 + 8 * c] = *(uint4*)hp;
        }
    }
}

// ---------- fused GAT per-dst, heads=1, fp16 H, fp32 out (R9 structure) ----------
__global__ __launch_bounds__(256) void gat_csr1(const int* __restrict__ offs,
                                                const int* __restrict__ csr_src,
                                                const float* __restrict__ AS,
                                                const float* __restrict__ AD,
                                                const __half* __restrict__ H,
                                                const float* __restrict__ bias,
                                                float* __restrict__ Out,
                                                int N, int do_relu) {
    __shared__ int   sS[4][64];
    __shared__ float sP[4][64];
    const int lane = threadIdx.x & 63;
    const int w = threadIdx.x >> 6;
    const int wid = (int)((blockIdx.x * blockDim.x + threadIdx.x) >> 6);
    const int nw = (int)((gridDim.x * blockDim.x) >> 6);
    const int c = lane & 15;     // channels 4c..4c+3
    const int slot = lane >> 4;  // 4 edge slots
    int* const sSw = &sS[w][0];
    float* const sPw = &sP[w][0];
    const float4 b4 = *(const float4*)&bias[4 * c];

    for (int n = wid; n < N; n += nw) {
        const int s0 = offs[n], s1 = offs[n + 1];
        const int deg = s1 - s0;
        const float adv0 = AD[n];
        float dn0 = 0.f, p0 = 0.f;
        int sreg = 0;
        for (int i = s0 + lane; i < s1; i += 64) {
            int s = csr_src[i];
            float e0 = AS[s] + adv0;
            e0 = e0 > 0.f ? e0 : NEG_SLOPE * e0;
            float pe0 = __expf(e0);
            dn0 += pe0;
            if (i == s0 + lane) { sreg = s; p0 = pe0; }
        }
        for (int o = 1; o < 64; o <<= 1) dn0 += __shfl_xor(dn0, o, 64);
        const float inv0 = 1.f / (dn0 + EPSF);

        float a[4];
#pragma unroll
        for (int j = 0; j < 4; ++j) a[j] = 0.f;
        if (deg <= 64) {
            sSw[lane] = sreg;
            sPw[lane] = p0;
            const int npc = (deg + 3) >> 2;
            int t = 0;
            for (; t + 4 <= npc; t += 4) {
                int ss[4]; float pw[4]; uint2 hv[4];
#pragma unroll
                for (int k = 0; k < 4; ++k) {
                    int idx = 4 * (t + k) + slot;
                    ss[k] = sSw[idx];
                    pw[k] = sPw[idx];
                }
#pragma unroll
                for (int k = 0; k < 4; ++k)
                    hv[k] = *(const uint2*)&H[(size_t)ss[k] * 64 + 4 * c];
#pragma unroll
                for (int k = 0; k < 4; ++k) {
                    const __half2* h2 = (const __half2*)&hv[k];
                    float2 f01 = __half22float2(h2[0]);
                    float2 f23 = __half22float2(h2[1]);
                    a[0] = fmaf(f01.x, pw[k], a[0]);
                    a[1] = fmaf(f01.y, pw[k], a[1]);
                    a[2] = fmaf(f23.x, pw[k], a[2]);
                    a[3] = fmaf(f23.y, pw[k], a[3]);
                }
            }
            for (; t < npc; ++t) {
                int idx = 4 * t + slot;
                int s = sSw[idx];
                float pw = sPw[idx];
                uint2 hv = *(const uint2*)&H[(size_t)s * 64 + 4 * c];
                const __half2* h2 = (const __half2*)&hv;
                float2 f01 = __half22float2(h2[0]);
                float2 f23 = __half22float2(h2[1]);
                a[0] = fmaf(f01.x, pw, a[0]);
                a[1] = fmaf(f01.y, pw, a[1]);
                a[2] = fmaf(f23.x, pw, a[2]);
                a[3] = fmaf(f23.y, pw, a[3]);
            }
        } else {
            for (int i = s0 + slot; i < s1; i += 4) {
                int s = csr_src[i];
                float e = AS[s] + adv0;
                e = e > 0.f ? e : NEG_SLOPE * e;
                float pw = __expf(e);
                uint2 hv = *(const uint2*)&H[(size_t)s * 64 + 4 * c];
                const __half2* h2 = (const __half2*)&hv;
                float2 f01 = __half22float2(h2[0]);
                float2 f23 = __half22float2(h2[1]);
                a[0] = fmaf(f01.x, pw, a[0]);
                a[1] = fmaf(f01.y, pw, a[1]);
                a[2] = fmaf(f23.x, pw, a[2]);
                a[3] = fmaf(f23.y, pw, a[3]);
            }
        }
#pragma unroll
        for (int j = 0; j < 4; ++j) {
            a[j] += __shfl_xor(a[j], 16, 64);
            a[j] += __shfl_xor(a[j], 32, 64);
        }
        if (lane < 16) {
            float4 o;
            o.x = a[0] * inv0 + b4.x;
            o.y = a[1] * inv0 + b4.y;
            o.z = a[2] * inv0 + b4.z;
            o.w = a[3] * inv0 + b4.w;
            if (do_relu) {
                o.x = fmaxf(o.x, 0.f); o.y = fmaxf(o.y, 0.f);
                o.z = fmaxf(o.z, 0.f); o.w = fmaxf(o.w, 0.f);
            }
            *(float4*)&Out[(size_t)n * 64 + 4 * c] = o;
        }
    }
}

extern "C" void kernel_launch(void* const* d_in, const int* in_sizes, int n_in,
                              void* d_out, int out_size, void* d_ws, size_t ws_size,
                              hipStream_t stream) {
    const float* x   = (const float*)d_in[0];
    const int*   ei  = (const int*)d_in[1];
    const float* W0  = (const float*)d_in[2];
    const float* as0 = (const float*)d_in[3];
    const float* ad0 = (const float*)d_in[4];
    const float* b0  = (const float*)d_in[5];
    const float* W1  = (const float*)d_in[6];
    const float* as1 = (const float*)d_in[7];
    const float* ad1 = (const float*)d_in[8];
    const float* b1  = (const float*)d_in[9];
    const float* W2  = (const float*)d_in[10];
    const float* as2 = (const float*)d_in[11];
    const float* ad2 = (const float*)d_in[12];
    const float* b2  = (const float*)d_in[13];

    const int N = in_sizes[0] / 128;
    const int E_raw = in_sizes[1] / 2;
    const int E = E_raw + N;

    char* ws = (char*)d_ws;
    size_t off = 0;
    auto alloc = [&](size_t bytes) {
        void* p = ws + off;
        off = (off + bytes + 255) & ~(size_t)255;
        return p;
    };
    __half* hh    = (__half*)alloc((size_t)N * 128 * 2);
    __half* obufh = (__half*)alloc((size_t)N * 128 * 2);
    float* asb  = (float*)alloc((size_t)N * 2 * 4);
    float* adb  = (float*)alloc((size_t)N * 2 * 4);
    int*   cnt  = (int*)alloc((size_t)(N + 4) * 4);
    int*   offs = (int*)alloc((size_t)(N + 1) * 4);
    int*   bsum = (int*)alloc(1024);
    int* csr_src = (int*)alloc((size_t)E * 4);
    (void)ws_size; (void)n_in; (void)out_size;

    // ---- build CSR grouped by dst (reused by all 3 layers) ----
    const int nb = (N + 255) / 256;
    const int n4 = (N + 3) / 4;
    zero_kernel<<<(n4 + 255) / 256, 256, 0, stream>>>(cnt, n4);
    hist_kernel<<<2048, 256, 0, stream>>>(ei, E_raw, N, cnt);
    scan_block<<<nb, 256, 0, stream>>>(cnt, offs, bsum, N);
    scan_bsum<<<1, 256, 0, stream>>>(bsum, nb);
    scan_add<<<nb, 256, 0, stream>>>(offs, bsum, N, E);
    scatter_edges_part<<<2048, 256, 0, stream>>>(ei, E_raw, N, cnt, offs, csr_src);

    const int gemm_blocks = (N + 63) / 64;
    // Cap grid: 2048 blocks x 4 waves = 8192 waves; each wave strides ~6 nodes.
    const int gat_blocks = 2048;

    // Layer 0: x (fp32) -> obufh (fp16, relu)
    gemm_fused<128, 2, true, float><<<gemm_blocks, 256, 0, stream>>>(x, W0, as0, ad0, nullptr, hh, asb, adb, N);
    gat_csr2<<<gat_blocks, 256, 0, stream>>>(offs, csr_src, asb, adb, hh, b0, obufh, N, 1);
    // Layer 1: obufh (fp16) -> obufh (fp16, relu)
    gemm_fused<128, 2, true, __half><<<gemm_blocks, 256, 0, stream>>>(obufh, W1, as1, ad1, nullptr, hh, asb, adb, N);
    gat_csr2<<<gat_blocks, 256, 0, stream>>>(offs, csr_src, asb, adb, hh, b1, obufh, N, 1);
    // Layer 2: obufh (fp16) -> d_out (fp32, heads=1, no relu); h stored fp16
    gemm_fused<64, 1, true, __half><<<gemm_blocks, 256, 0, stream>>>(obufh, W2, as2, ad2, nullptr, hh, asb, adb, N);
    gat_csr1<<<gat_blocks, 256, 0, stream>>>(offs, csr_src, asb, adb, hh, b2, (float*)d_out, N, 0);
}

// Round 13
// 257.234 us; speedup vs baseline: 1.1814x; 1.0699x over previous
//
#include <hip/hip_runtime.h>
#include <hip/hip_fp16.h>

#define NEG_SLOPE 0.2f
#define EPSF 1e-16f

typedef _Float16 half8 __attribute__((ext_vector_type(8)));
typedef float floatx4 __attribute__((ext_vector_type(4)));

// ---------- x (fp32) -> fp16 ----------
__global__ void to_half_kernel(const float* __restrict__ in, __half* __restrict__ out,
                               int n8) {
    int i = blockIdx.x * blockDim.x + threadIdx.x;
    if (i < n8) {
        float4 a = ((const float4*)in)[i * 2];
        float4 b = ((const float4*)in)[i * 2 + 1];
        __half2 hp[4];
        hp[0] = __floats2half2_rn(a.x, a.y);
        hp[1] = __floats2half2_rn(a.z, a.w);
        hp[2] = __floats2half2_rn(b.x, b.y);
        hp[3] = __floats2half2_rn(b.z, b.w);
        ((uint4*)out)[i] = *(uint4*)hp;
    }
}

// ---------- MFMA fp16 GEMM + fused alpha epilogue ----------
// C[M,BN] = X[M,128] @ W[128,BN]; X fp16, W fp32 (converted to fp16 in LDS),
// fp32 MFMA accum. Per wave: 16 rows x BN. A from global, B from LDS Wt[n][k].
// Layouts (gfx950 16x16x32): A row=lane&15, k=8*(lane>>4)+i; B col=lane&15,
// same k; C/D col=lane&15, row=4*(lane>>4)+reg  [guide-verified].
template<int BN, int HEADS>
__global__ __launch_bounds__(256) void gemm_mfma(const __half* __restrict__ X,
                                                 const float* __restrict__ W,
                                                 const float* __restrict__ asrc,
                                                 const float* __restrict__ adst,
                                                 __half* __restrict__ OutH,
                                                 float* __restrict__ AS,
                                                 float* __restrict__ AD, int N) {
    constexpr int KP = 136;           // padded k-stride (f16) for Wt
    constexpr int NF = BN / 16;       // 8 (BN=128) or 4 (BN=64)
    __shared__ _Float16 Wt[BN][KP];
    const int tid = threadIdx.x;
    const int wave = tid >> 6, lane = tid & 63;
    const int r = lane & 15;          // A-row-in-tile / B,C col-in-frag
    const int g = lane >> 4;          // k-group / C row-group
    const int row0 = blockIdx.x * 64 + wave * 16;

    // stage Wt[n][k] = (f16) W[k][n]
    for (int idx = tid; idx < 128 * (BN / 4); idx += 256) {
        int k = idx / (BN / 4), n4 = idx % (BN / 4);
        float4 w4 = *(const float4*)&W[(size_t)k * BN + n4 * 4];
        Wt[n4 * 4 + 0][k] = (_Float16)w4.x;
        Wt[n4 * 4 + 1][k] = (_Float16)w4.y;
        Wt[n4 * 4 + 2][k] = (_Float16)w4.z;
        Wt[n4 * 4 + 3][k] = (_Float16)w4.w;
    }
    __syncthreads();

    const int arow = row0 + r;
    const int arow_c = (arow < N) ? arow : (N - 1);   // clamp; bad rows never stored

    floatx4 acc[NF];
#pragma unroll
    for (int n = 0; n < NF; ++n) acc[n] = (floatx4)(0.f);

#pragma unroll
    for (int ks = 0; ks < 4; ++ks) {   // K-steps of 32
        half8 afrag = *(const half8*)&X[(size_t)arow_c * 128 + ks * 32 + g * 8];
#pragma unroll
        for (int n = 0; n < NF; ++n) {
            half8 bfrag = *(const half8*)&Wt[n * 16 + r][ks * 32 + g * 8];
            acc[n] = __builtin_amdgcn_mfma_f32_16x16x32_f16(afrag, bfrag, acc[n], 0, 0, 0);
        }
    }

    float av[NF], dv[NF];
#pragma unroll
    for (int n = 0; n < NF; ++n) { av[n] = asrc[n * 16 + r]; dv[n] = adst[n * 16 + r]; }

#pragma unroll
    for (int reg = 0; reg < 4; ++reg) {
        const int orow = row0 + g * 4 + reg;   // uniform across the 16-lane r-group
        if (orow >= N) continue;
#pragma unroll
        for (int n = 0; n < NF; ++n)
            OutH[(size_t)orow * BN + n * 16 + r] = __float2half(acc[n][reg]);
        float ps0 = 0.f, pd0 = 0.f, ps1 = 0.f, pd1 = 0.f;
#pragma unroll
        for (int n = 0; n < NF; ++n) {
            float v = acc[n][reg];
            if (HEADS == 2 && n >= NF / 2) { ps1 = fmaf(v, av[n], ps1); pd1 = fmaf(v, dv[n], pd1); }
            else                           { ps0 = fmaf(v, av[n], ps0); pd0 = fmaf(v, dv[n], pd0); }
        }
#pragma unroll
        for (int o = 1; o < 16; o <<= 1) {
            ps0 += __shfl_xor(ps0, o, 64); pd0 += __shfl_xor(pd0, o, 64);
            if (HEADS == 2) { ps1 += __shfl_xor(ps1, o, 64); pd1 += __shfl_xor(pd1, o, 64); }
        }
        if (r == 0) {
            if (HEADS == 2) {
                AS[orow * 2] = ps0; AS[orow * 2 + 1] = ps1;
                AD[orow * 2] = pd0; AD[orow * 2 + 1] = pd1;
            } else {
                AS[orow] = ps0; AD[orow] = pd0;
            }
        }
    }
}

// ---------- CSR build ----------
__global__ void zero_kernel(int* __restrict__ p, int n4) {
    int i = blockIdx.x * blockDim.x + threadIdx.x;
    if (i < n4) ((int4*)p)[i] = make_int4(0, 0, 0, 0);
}

// XCD-partitioned histogram: atomics to cnt[d] only from one blockIdx%8 group
// (same cross-XCD line ping-pong fix as scatter_edges_part).
__global__ void hist_part(const int* __restrict__ ei, int E_raw, int N,
                          int* __restrict__ cnt) {
    const int NPART = 8;
    const int part = blockIdx.x & (NPART - 1);
    const int gblocks = gridDim.x >> 3;
    const int grank = blockIdx.x >> 3;
    const int tid = grank * blockDim.x + threadIdx.x;
    const int nthr = gblocks * blockDim.x;
    const int E = E_raw + N;
    const int dlo = (int)(((long long)N * part) / NPART);
    const int dhi = (int)(((long long)N * (part + 1)) / NPART);
    for (int e = tid; e < E; e += nthr) {
        int d = (e < E_raw) ? ei[E_raw + e] : e - E_raw;
        if (d >= dlo && d < dhi) atomicAdd(&cnt[d], 1);
    }
}

__global__ __launch_bounds__(256) void scan_block(const int* __restrict__ cnt,
                                                  int* __restrict__ offs,
                                                  int* __restrict__ bsum, int N) {
    __shared__ int wsum[4];
    const int i = blockIdx.x * 256 + threadIdx.x;
    const int lane = threadIdx.x & 63, w = threadIdx.x >> 6;
    int v = (i < N) ? cnt[i] : 0;
    int incl = v;
    for (int o = 1; o < 64; o <<= 1) {
        int t = __shfl_up(incl, o, 64);
        if (lane >= o) incl += t;
    }
    if (lane == 63) wsum[w] = incl;
    __syncthreads();
    int prefix = 0;
    for (int k = 0; k < w; ++k) prefix += wsum[k];
    if (i < N) offs[i] = prefix + incl - v;
    if (threadIdx.x == 255) bsum[blockIdx.x] = prefix + incl;
}

__global__ __launch_bounds__(256) void scan_bsum(int* __restrict__ bsum, int nb) {
    __shared__ int wsum[4];
    const int lane = threadIdx.x & 63, w = threadIdx.x >> 6;
    int v = (threadIdx.x < nb) ? bsum[threadIdx.x] : 0;
    int incl = v;
    for (int o = 1; o < 64; o <<= 1) {
        int t = __shfl_up(incl, o, 64);
        if (lane >= o) incl += t;
    }
    if (lane == 63) wsum[w] = incl;
    __syncthreads();
    int prefix = 0;
    for (int k = 0; k < w; ++k) prefix += wsum[k];
    if (threadIdx.x < nb) bsum[threadIdx.x] = prefix + incl - v;
}

__global__ void scan_add(int* __restrict__ offs, const int* __restrict__ bsum,
                         int N, int E) {
    const int i = blockIdx.x * 256 + threadIdx.x;
    if (i < N) offs[i] += bsum[blockIdx.x];
    if (i == 0) offs[N] = E;
}

// XCD-partitioned scatter (R5). pos = offs[d] + (--cnt[d]); cnt ends at 0.
__global__ void scatter_edges_part(const int* __restrict__ ei, int E_raw, int N,
                                   int* __restrict__ cnt,
                                   const int* __restrict__ offs,
                                   int* __restrict__ csr_src) {
    const int NPART = 8;
    const int part = blockIdx.x & (NPART - 1);
    const int gblocks = gridDim.x >> 3;
    const int grank = blockIdx.x >> 3;
    const int tid = grank * blockDim.x + threadIdx.x;
    const int nthr = gblocks * blockDim.x;
    const int E = E_raw + N;
    const int dlo = (int)(((long long)N * part) / NPART);
    const int dhi = (int)(((long long)N * (part + 1)) / NPART);
    for (int e = tid; e < E; e += nthr) {
        int d = (e < E_raw) ? ei[E_raw + e] : e - E_raw;
        if (d >= dlo && d < dhi) {
            int s = (e < E_raw) ? ei[e] : d;
            int old = atomicSub(&cnt[d], 1);
            csr_src[offs[d] + old - 1] = s;
        }
    }
}

// ---------- fused GAT per-dst, heads=2, fp16 H, fp16 out (R12 best) ----------
__global__ __launch_bounds__(256) void gat_csr2(const int* __restrict__ offs,
                                                const int* __restrict__ csr_src,
                                                const float* __restrict__ AS,
                                                const float* __restrict__ AD,
                                                const __half* __restrict__ H,
                                                const float* __restrict__ bias,
                                                __half* __restrict__ Out,
                                                int N, int do_relu) {
    __shared__ int   sS[4][64];
    __shared__ float sP0[4][64];
    __shared__ float sP1[4][64];
    const int lane = threadIdx.x & 63;
    const int w = threadIdx.x >> 6;
    const int wid = (int)((blockIdx.x * blockDim.x + threadIdx.x) >> 6);
    const int nw = (int)((gridDim.x * blockDim.x) >> 6);
    const int c = lane & 15;      // channels 8c..8c+7
    const int slot = lane >> 4;   // 4 edge slots
    const int myh = c >> 3;       // head owning my channels
    int* const sSw = &sS[w][0];
    const float* const myp = myh ? &sP1[w][0] : &sP0[w][0];
    const float4 bA = *(const float4*)&bias[8 * c];
    const float4 bB = *(const float4*)&bias[8 * c + 4];

    for (int n = wid; n < N; n += nw) {
        const int s0 = offs[n], s1 = offs[n + 1];
        const int deg = s1 - s0;
        const float2 adv = *(const float2*)&AD[(size_t)n * 2];
        float dn0 = 0.f, dn1 = 0.f, p0 = 0.f, p1 = 0.f;
        int sreg = 0;
        for (int i = s0 + lane; i < s1; i += 64) {
            int s = csr_src[i];
            float2 a2 = *(const float2*)&AS[(size_t)s * 2];
            float e0 = a2.x + adv.x, e1 = a2.y + adv.y;
            e0 = e0 > 0.f ? e0 : NEG_SLOPE * e0;
            e1 = e1 > 0.f ? e1 : NEG_SLOPE * e1;
            float pe0 = __expf(e0), pe1 = __expf(e1);
            dn0 += pe0; dn1 += pe1;
            if (i == s0 + lane) { sreg = s; p0 = pe0; p1 = pe1; }
        }
        for (int o = 1; o < 64; o <<= 1) {
            dn0 += __shfl_xor(dn0, o, 64);
            dn1 += __shfl_xor(dn1, o, 64);
        }
        const float myinv = 1.f / ((myh ? dn1 : dn0) + EPSF);

        float a[8];
#pragma unroll
        for (int j = 0; j < 8; ++j) a[j] = 0.f;
        if (deg <= 64) {
            sSw[lane] = sreg;       // phantom lanes: s=0, p=0
            sP0[w][lane] = p0;
            sP1[w][lane] = p1;
            const int npc = (deg + 3) >> 2;   // quads; phantom edges have p=0
            int t = 0;
            for (; t + 4 <= npc; t += 4) {
                int ss[4]; float pw[4]; uint4 hv[4];
#pragma unroll
                for (int k = 0; k < 4; ++k) {
                    int idx = 4 * (t + k) + slot;
                    ss[k] = sSw[idx];
                    pw[k] = myp[idx];
                }
#pragma unroll
                for (int k = 0; k < 4; ++k)
                    hv[k] = *(const uint4*)&H[(size_t)ss[k] * 128 + 8 * c];
#pragma unroll
                for (int k = 0; k < 4; ++k) {
                    const __half2* h2 = (const __half2*)&hv[k];
#pragma unroll
                    for (int j = 0; j < 4; ++j) {
                        float2 f = __half22float2(h2[j]);
                        a[2 * j]     = fmaf(f.x, pw[k], a[2 * j]);
                        a[2 * j + 1] = fmaf(f.y, pw[k], a[2 * j + 1]);
                    }
                }
            }
            for (; t < npc; ++t) {
                int idx = 4 * t + slot;
                int s = sSw[idx];
                float pw = myp[idx];
                uint4 hv = *(const uint4*)&H[(size_t)s * 128 + 8 * c];
                const __half2* h2 = (const __half2*)&hv;
#pragma unroll
                for (int j = 0; j < 4; ++j) {
                    float2 f = __half22float2(h2[j]);
                    a[2 * j]     = fmaf(f.x, pw, a[2 * j]);
                    a[2 * j + 1] = fmaf(f.y, pw, a[2 * j + 1]);
                }
            }
        } else {
            const float advh = myh ? adv.y : adv.x;
            for (int i = s0 + slot; i < s1; i += 4) {
                int s = csr_src[i];
                float e = AS[(size_t)s * 2 + myh] + advh;
                e = e > 0.f ? e : NEG_SLOPE * e;
                float pw = __expf(e);
                uint4 hv = *(const uint4*)&H[(size_t)s * 128 + 8 * c];
                const __half2* h2 = (const __half2*)&hv;
#pragma unroll
                for (int j = 0; j < 4; ++j) {
                    float2 f = __half22float2(h2[j]);
                    a[2 * j]     = fmaf(f.x, pw, a[2 * j]);
                    a[2 * j + 1] = fmaf(f.y, pw, a[2 * j + 1]);
                }
            }
        }
#pragma unroll
        for (int j = 0; j < 8; ++j) {
            a[j] += __shfl_xor(a[j], 16, 64);
            a[j] += __shfl_xor(a[j], 32, 64);
        }
        if (lane < 16) {
            float o[8];
            o[0] = a[0] * myinv + bA.x; o[1] = a[1] * myinv + bA.y;
            o[2] = a[2] * myinv + bA.z; o[3] = a[3] * myinv + bA.w;
            o[4] = a[4] * myinv + bB.x; o[5] = a[5] * myinv + bB.y;
            o[6] = a[6] * myinv + bB.z; o[7] = a[7] * myinv + bB.w;
            if (do_relu) {
#pragma unroll
                for (int j = 0; j < 8; ++j) o[j] = fmaxf(o[j], 0.f);
            }
            __half2 hp[4];
#pragma unroll
            for (int j = 0; j < 4; ++j) hp[j] = __floats2half2_rn(o[2 * j], o[2 * j + 1]);
            *(uint4*)&Out[(size_t)n * 128 + 8 * c] = *(uint4*)hp;
        }
    }
}

// ---------- fused GAT per-dst, heads=1, fp16 H, fp32 out (R12 best) ----------
__global__ __launch_bounds__(256) void gat_csr1(const int* __restrict__ offs,
                                                const int* __restrict__ csr_src,
                                                const float* __restrict__ AS,
                                                const float* __restrict__ AD,
                                                const __half* __restrict__ H,
                                                const float* __restrict__ bias,
                                                float* __restrict__ Out,
                                                int N, int do_relu) {
    __shared__ int   sS[4][64];
    __shared__ float sP[4][64];
    const int lane = threadIdx.x & 63;
    const int w = threadIdx.x >> 6;
    const int wid = (int)((blockIdx.x * blockDim.x + threadIdx.x) >> 6);
    const int nw = (int)((gridDim.x * blockDim.x) >> 6);
    const int c = lane & 15;     // channels 4c..4c+3
    const int slot = lane >> 4;  // 4 edge slots
    int* const sSw = &sS[w][0];
    float* const sPw = &sP[w][0];
    const float4 b4 = *(const float4*)&bias[4 * c];

    for (int n = wid; n < N; n += nw) {
        const int s0 = offs[n], s1 = offs[n + 1];
        const int deg = s1 - s0;
        const float adv0 = AD[n];
        float dn0 = 0.f, p0 = 0.f;
        int sreg = 0;
        for (int i = s0 + lane; i < s1; i += 64) {
            int s = csr_src[i];
            float e0 = AS[s] + adv0;
            e0 = e0 > 0.f ? e0 : NEG_SLOPE * e0;
            float pe0 = __expf(e0);
            dn0 += pe0;
            if (i == s0 + lane) { sreg = s; p0 = pe0; }
        }
        for (int o = 1; o < 64; o <<= 1) dn0 += __shfl_xor(dn0, o, 64);
        const float inv0 = 1.f / (dn0 + EPSF);

        float a[4];
#pragma unroll
        for (int j = 0; j < 4; ++j) a[j] = 0.f;
        if (deg <= 64) {
            sSw[lane] = sreg;
            sPw[lane] = p0;
            const int npc = (deg + 3) >> 2;
            int t = 0;
            for (; t + 4 <= npc; t += 4) {
                int ss[4]; float pw[4]; uint2 hv[4];
#pragma unroll
                for (int k = 0; k < 4; ++k) {
                    int idx = 4 * (t + k) + slot;
                    ss[k] = sSw[idx];
                    pw[k] = sPw[idx];
                }
#pragma unroll
                for (int k = 0; k < 4; ++k)
                    hv[k] = *(const uint2*)&H[(size_t)ss[k] * 64 + 4 * c];
#pragma unroll
                for (int k = 0; k < 4; ++k) {
                    const __half2* h2 = (const __half2*)&hv[k];
                    float2 f01 = __half22float2(h2[0]);
                    float2 f23 = __half22float2(h2[1]);
                    a[0] = fmaf(f01.x, pw[k], a[0]);
                    a[1] = fmaf(f01.y, pw[k], a[1]);
                    a[2] = fmaf(f23.x, pw[k], a[2]);
                    a[3] = fmaf(f23.y, pw[k], a[3]);
                }
            }
            for (; t < npc; ++t) {
                int idx = 4 * t + slot;
                int s = sSw[idx];
                float pw = sPw[idx];
                uint2 hv = *(const uint2*)&H[(size_t)s * 64 + 4 * c];
                const __half2* h2 = (const __half2*)&hv;
                float2 f01 = __half22float2(h2[0]);
                float2 f23 = __half22float2(h2[1]);
                a[0] = fmaf(f01.x, pw, a[0]);
                a[1] = fmaf(f01.y, pw, a[1]);
                a[2] = fmaf(f23.x, pw, a[2]);
                a[3] = fmaf(f23.y, pw, a[3]);
            }
        } else {
            for (int i = s0 + slot; i < s1; i += 4) {
                int s = csr_src[i];
                float e = AS[s] + adv0;
                e = e > 0.f ? e : NEG_SLOPE * e;
                float pw = __expf(e);
                uint2 hv = *(const uint2*)&H[(size_t)s * 64 + 4 * c];
                const __half2* h2 = (const __half2*)&hv;
                float2 f01 = __half22float2(h2[0]);
                float2 f23 = __half22float2(h2[1]);
                a[0] = fmaf(f01.x, pw, a[0]);
                a[1] = fmaf(f01.y, pw, a[1]);
                a[2] = fmaf(f23.x, pw, a[2]);
                a[3] = fmaf(f23.y, pw, a[3]);
            }
        }
#pragma unroll
        for (int j = 0; j < 4; ++j) {
            a[j] += __shfl_xor(a[j], 16, 64);
            a[j] += __shfl_xor(a[j], 32, 64);
        }
        if (lane < 16) {
            float4 o;
            o.x = a[0] * inv0 + b4.x;
            o.y = a[1] * inv0 + b4.y;
            o.z = a[2] * inv0 + b4.z;
            o.w = a[3] * inv0 + b4.w;
            if (do_relu) {
                o.x = fmaxf(o.x, 0.f); o.y = fmaxf(o.y, 0.f);
                o.z = fmaxf(o.z, 0.f); o.w = fmaxf(o.w, 0.f);
            }
            *(float4*)&Out[(size_t)n * 64 + 4 * c] = o;
        }
    }
}

extern "C" void kernel_launch(void* const* d_in, const int* in_sizes, int n_in,
                              void* d_out, int out_size, void* d_ws, size_t ws_size,
                              hipStream_t stream) {
    const float* x   = (const float*)d_in[0];
    const int*   ei  = (const int*)d_in[1];
    const float* W0  = (const float*)d_in[2];
    const float* as0 = (const float*)d_in[3];
    const float* ad0 = (const float*)d_in[4];
    const float* b0  = (const float*)d_in[5];
    const float* W1  = (const float*)d_in[6];
    const float* as1 = (const float*)d_in[7];
    const float* ad1 = (const float*)d_in[8];
    const float* b1  = (const float*)d_in[9];
    const float* W2  = (const float*)d_in[10];
    const float* as2 = (const float*)d_in[11];
    const float* ad2 = (const float*)d_in[12];
    const float* b2  = (const float*)d_in[13];

    const int N = in_sizes[0] / 128;
    const int E_raw = in_sizes[1] / 2;
    const int E = E_raw + N;

    char* ws = (char*)d_ws;
    size_t off = 0;
    auto alloc = [&](size_t bytes) {
        void* p = ws + off;
        off = (off + bytes + 255) & ~(size_t)255;
        return p;
    };
    __half* xh    = (__half*)alloc((size_t)N * 128 * 2);  // x in fp16
    __half* hh    = (__half*)alloc((size_t)N * 128 * 2);  // h (fp16)
    __half* obufh = (__half*)alloc((size_t)N * 128 * 2);  // inter-layer acts fp16
    float* asb  = (float*)alloc((size_t)N * 2 * 4);
    float* adb  = (float*)alloc((size_t)N * 2 * 4);
    int*   cnt  = (int*)alloc((size_t)(N + 4) * 4);
    int*   offs = (int*)alloc((size_t)(N + 1) * 4);
    int*   bsum = (int*)alloc(1024);
    int* csr_src = (int*)alloc((size_t)E * 4);
    (void)ws_size; (void)n_in; (void)out_size;

    // ---- build CSR grouped by dst (reused by all 3 layers) ----
    const int nb = (N + 255) / 256;
    const int n4 = (N + 3) / 4;
    zero_kernel<<<(n4 + 255) / 256, 256, 0, stream>>>(cnt, n4);
    hist_part<<<2048, 256, 0, stream>>>(ei, E_raw, N, cnt);
    scan_block<<<nb, 256, 0, stream>>>(cnt, offs, bsum, N);
    scan_bsum<<<1, 256, 0, stream>>>(bsum, nb);
    scan_add<<<nb, 256, 0, stream>>>(offs, bsum, N, E);
    scatter_edges_part<<<2048, 256, 0, stream>>>(ei, E_raw, N, cnt, offs, csr_src);

    // x -> fp16 (overlaps CSR build in-stream)
    const int n8 = N * 128 / 8;
    to_half_kernel<<<(n8 + 255) / 256, 256, 0, stream>>>(x, xh, n8);

    const int gemm_blocks = (N + 63) / 64;
    const int gat_blocks = 2048;

    // Layer 0: xh -> obufh (fp16, relu)
    gemm_mfma<128, 2><<<gemm_blocks, 256, 0, stream>>>(xh, W0, as0, ad0, hh, asb, adb, N);
    gat_csr2<<<gat_blocks, 256, 0, stream>>>(offs, csr_src, asb, adb, hh, b0, obufh, N, 1);
    // Layer 1: obufh -> obufh (fp16, relu)
    gemm_mfma<128, 2><<<gemm_blocks, 256, 0, stream>>>(obufh, W1, as1, ad1, hh, asb, adb, N);
    gat_csr2<<<gat_blocks, 256, 0, stream>>>(offs, csr_src, asb, adb, hh, b1, obufh, N, 1);
    // Layer 2: obufh -> d_out (fp32, heads=1, no relu); h stored fp16
    gemm_mfma<64, 1><<<gemm_blocks, 256, 0, stream>>>(obufh, W2, as2, ad2, hh, asb, adb, N);
    gat_csr1<<<gat_blocks, 256, 0, stream>>>(offs, csr_src, asb, adb, hh, b2, (float*)d_out, N, 0);
}